// Round 9
// baseline (748.167 us; speedup 1.0000x reference)
//
#include <hip/hip_runtime.h>

#define N_NODES 100000
#define N_EDGES 1600000
#define N_GRAPHS 1024
#define D 128
#define NL 3
#define BN_EPS 1e-5f
#define BG 196                                  // dst nodes per bucket
#define NB ((N_NODES + BG - 1) / BG)            // 511 buckets
#define EPB 16384                               // edges per k_part block

typedef __attribute__((ext_vector_type(8))) short bf16x8;
typedef __attribute__((ext_vector_type(4))) float f32x4;

__device__ __forceinline__ unsigned short f2b(float f) {
    unsigned int u = __float_as_uint(f);
    u += 0x7fff + ((u >> 16) & 1);   // round to nearest even
    return (unsigned short)(u >> 16);
}
__device__ __forceinline__ float b2f(unsigned short b) {
    return __uint_as_float(((unsigned int)b) << 16);
}

__device__ __forceinline__ int geti(const void* p, long long i, int f64) {
    return f64 ? (int)((const long long*)p)[i] : ((const int*)p)[i];
}

__global__ void k_detect(const void* ei, int* flag) {
    int t = threadIdx.x;
    const int* p = (const int*)ei;
    int acc = p[2 * t + 1] | p[2 * (t + 64) + 1];
    unsigned long long b = __ballot(acc != 0);
    if (t == 0) *flag = (b == 0ULL) ? 1 : 0;
}

// ---------------- weight prep: Wt[m][n][k] = bf16(W[m][k][n]) ----------------
__global__ void k_wprep(const float* __restrict__ W1, const float* __restrict__ W2,
                        unsigned short* __restrict__ Wt) {
    int m = blockIdx.y;
    int k = blockIdx.x;
    int n = threadIdx.x;
    const float* src = (m < NL) ? (W1 + (size_t)m * D * D) : (W2 + (size_t)(m - NL) * D * D);
    Wt[(size_t)m * D * D + n * D + k] = f2b(src[k * D + n]);
}

// ---------------- CSR build ----------------
__global__ void k_hist(const void* ei, const int* __restrict__ flag, int* __restrict__ deg) {
    int e = blockIdx.x * 256 + threadIdx.x;
    int f = *flag;
    if (e < N_EDGES) {
        int d = geti(ei, (long long)N_EDGES + e, f);
        atomicAdd(&deg[d], 1);
    }
}

__global__ void k_scan1(const int* __restrict__ deg, int* __restrict__ bsum) {
    __shared__ int wsum[4];
    int tid = threadIdx.x;
    int base = blockIdx.x * 1024 + tid * 4;
    int s = 0;
#pragma unroll
    for (int j = 0; j < 4; ++j) {
        int idx = base + j;
        if (idx < N_NODES) s += deg[idx];
    }
    for (int off = 32; off > 0; off >>= 1) s += __shfl_down(s, off, 64);
    if ((tid & 63) == 0) wsum[tid >> 6] = s;
    __syncthreads();
    if (tid == 0) bsum[blockIdx.x] = wsum[0] + wsum[1] + wsum[2] + wsum[3];
}

__global__ void k_scan2(const int* __restrict__ bsum, int* __restrict__ boff,
                        int* __restrict__ rowp) {
    if (threadIdx.x == 0) {
        int run = 0;
        for (int b = 0; b < 98; ++b) {
            boff[b] = run;
            run += bsum[b];
        }
        rowp[N_NODES] = run;
    }
}

__global__ void k_scan3(const int* __restrict__ deg, const int* __restrict__ boff,
                        int* __restrict__ rowp) {
    __shared__ int wsum[4];
    int tid = threadIdx.x;
    int lane = tid & 63;
    int w = tid >> 6;
    int base = blockIdx.x * 1024 + tid * 4;
    int d[4];
    int tot = 0;
#pragma unroll
    for (int j = 0; j < 4; ++j) {
        int idx = base + j;
        d[j] = (idx < N_NODES) ? deg[idx] : 0;
        tot += d[j];
    }
    int incl = tot;
    for (int off = 1; off < 64; off <<= 1) {
        int v = __shfl_up(incl, off, 64);
        if (lane >= off) incl += v;
    }
    if (lane == 63) wsum[w] = incl;
    __syncthreads();
    int woff = boff[blockIdx.x];
    for (int w2 = 0; w2 < w; ++w2) woff += wsum[w2];
    int ex = woff + incl - tot;
#pragma unroll
    for (int j = 0; j < 4; ++j) {
        int idx = base + j;
        if (idx < N_NODES) rowp[idx] = ex;
        ex += d[j];
    }
}

__global__ void k_gcur(const int* __restrict__ rowp, int* __restrict__ gcur) {
    int b = blockIdx.x * 256 + threadIdx.x;
    if (b < NB) gcur[b] = rowp[min(b * BG, N_NODES)];
}

__global__ __launch_bounds__(256) void k_part(const void* ei, const int* __restrict__ flag,
                                              int* __restrict__ gcur,
                                              unsigned int* __restrict__ tmp) {
    __shared__ int hist[NB + 1];
    __shared__ int cur[NB + 1];
    int tid = threadIdx.x;
    long long e0 = (long long)blockIdx.x * EPB;
    int f = *flag;
    for (int b = tid; b < NB; b += 256) hist[b] = 0;
    __syncthreads();
    for (int i = 0; i < EPB / 256; ++i) {
        long long e = e0 + i * 256 + tid;
        if (e < N_EDGES) {
            int d = geti(ei, (long long)N_EDGES + e, f);
            atomicAdd(&hist[d / BG], 1);
        }
    }
    __syncthreads();
    for (int b = tid; b < NB; b += 256) {
        int h = hist[b];
        cur[b] = h ? atomicAdd(&gcur[b], h) : 0;
    }
    __syncthreads();
    for (int i = 0; i < EPB / 256; ++i) {
        long long e = e0 + i * 256 + tid;
        if (e < N_EDGES) {
            int d = geti(ei, (long long)N_EDGES + e, f);
            int s = geti(ei, e, f);
            int b = d / BG;
            int pos = atomicAdd(&cur[b], 1);
            tmp[pos] = ((unsigned int)(d - b * BG) << 17) | (unsigned int)s;
        }
    }
}

__global__ __launch_bounds__(256) void k_fscat(const unsigned int* __restrict__ tmp,
                                               const int* __restrict__ rowp,
                                               int* __restrict__ eidx) {
    __shared__ int cur[BG];
    __shared__ int s_se[2];
    int b = blockIdx.x;
    int nb = b * BG;
    int nn = min(BG, N_NODES - nb);
    int tid = threadIdx.x;
    if (tid < nn) cur[tid] = rowp[nb + tid];
    if (tid == 0) s_se[0] = rowp[nb];
    if (tid == 1) s_se[1] = rowp[nb + nn];
    __syncthreads();
    for (int t = s_se[0] + tid; t < s_se[1]; t += 256) {
        unsigned int u = tmp[t];
        int dl = u >> 17;
        int pos = atomicAdd(&cur[dl], 1);
        eidx[pos] = (int)(u & 0x1FFFF);
    }
}

// ---------------- GEMM0: u0 = bf16(x) @ W1_0 (fp32 A direct, W in LDS) -------
__global__ __launch_bounds__(256) void k_gemm0(const float* __restrict__ x,
                                               const unsigned short* __restrict__ Wt,
                                               unsigned short* __restrict__ ub) {
    __shared__ unsigned short Ws[128 * 136];
    int tid = threadIdx.x;
    int row0 = blockIdx.x * 128;
#pragma unroll
    for (int i = 0; i < 8; ++i) {
        int chunk = tid + 256 * i;
        int n = chunk >> 4;
        int k8 = (chunk & 15) * 8;
        *(bf16x8*)&Ws[n * 136 + k8] = *(const bf16x8*)&Wt[n * 128 + k8];
    }
    __syncthreads();

    int w = tid >> 6, lane = tid & 63, q = lane >> 4, ln = lane & 15;
    int rbase = row0 + (w & 1) * 64, cbase = (w >> 1) * 64;

    f32x4 acc[4][4];
    f32x4 z4 = {0.f, 0.f, 0.f, 0.f};
#pragma unroll
    for (int rt = 0; rt < 4; ++rt)
#pragma unroll
        for (int ct = 0; ct < 4; ++ct) acc[rt][ct] = z4;

#pragma unroll
    for (int ks = 0; ks < 4; ++ks) {
        int ko = ks * 32 + q * 8;
        bf16x8 af[4];
#pragma unroll
        for (int rt = 0; rt < 4; ++rt) {
            int row = rbase + rt * 16 + ln;
            bf16x8 v = {0, 0, 0, 0, 0, 0, 0, 0};
            if (row < N_NODES) {
                float4 p0 = *(const float4*)&x[(size_t)row * 128 + ko];
                float4 p1 = *(const float4*)&x[(size_t)row * 128 + ko + 4];
                v[0] = (short)f2b(p0.x); v[1] = (short)f2b(p0.y);
                v[2] = (short)f2b(p0.z); v[3] = (short)f2b(p0.w);
                v[4] = (short)f2b(p1.x); v[5] = (short)f2b(p1.y);
                v[6] = (short)f2b(p1.z); v[7] = (short)f2b(p1.w);
            }
            af[rt] = v;
        }
        bf16x8 bfr[4];
#pragma unroll
        for (int ct = 0; ct < 4; ++ct)
            bfr[ct] = *(bf16x8*)&Ws[(cbase + ct * 16 + ln) * 136 + ko];
#pragma unroll
        for (int rt = 0; rt < 4; ++rt)
#pragma unroll
            for (int ct = 0; ct < 4; ++ct)
                acc[rt][ct] = __builtin_amdgcn_mfma_f32_16x16x32_bf16(af[rt], bfr[ct],
                                                                      acc[rt][ct], 0, 0, 0);
    }
#pragma unroll
    for (int rt = 0; rt < 4; ++rt) {
        int gr0 = rbase + rt * 16 + q * 4;
#pragma unroll
        for (int i = 0; i < 4; ++i) {
            int gr = gr0 + i;
            if (gr < N_NODES) {
#pragma unroll
                for (int ct = 0; ct < 4; ++ct)
                    ub[(size_t)gr * 128 + cbase + ct * 16 + ln] = f2b(acc[rt][ct][i]);
            }
        }
    }
}

// ---- aggregation in u-space: z = u_i + sum_j u_j + b1; BN stats fused -------
// 16 nodes per wave (keeps stats global atomics at ~400K); fp32 accumulate.
__global__ void k_agz(const unsigned short* __restrict__ ub, const int* __restrict__ rowp,
                      const int* __restrict__ eidx, const float* __restrict__ b1,
                      float* __restrict__ stats, unsigned short* __restrict__ zb) {
    __shared__ float s_sum[128];
    __shared__ float s_sq[128];
    int tid = threadIdx.x;
    if (tid < 128) {
        s_sum[tid] = 0.f;
        s_sq[tid] = 0.f;
    }
    __syncthreads();
    int wid = tid >> 6, lane = tid & 63;
    const unsigned int* u1 = (const unsigned int*)ub;
    float b1x = b1[2 * lane], b1y = b1[2 * lane + 1];
    float psx = 0.f, psy = 0.f, pqx = 0.f, pqy = 0.f;
    int base = (blockIdx.x * 4 + wid) * 16;
    for (int t = 0; t < 16; ++t) {
        int node = base + t;
        if (node >= N_NODES) break;
        unsigned int u = u1[(size_t)node * 64 + lane];
        float accx = __uint_as_float(u << 16);
        float accy = __uint_as_float(u & 0xffff0000u);
        int s = rowp[node], e = rowp[node + 1];
        int i = s;
        for (; i + 3 < e; i += 4) {
            unsigned int v0 = u1[(size_t)eidx[i] * 64 + lane];
            unsigned int v1 = u1[(size_t)eidx[i + 1] * 64 + lane];
            unsigned int v2 = u1[(size_t)eidx[i + 2] * 64 + lane];
            unsigned int v3 = u1[(size_t)eidx[i + 3] * 64 + lane];
            accx += __uint_as_float(v0 << 16) + __uint_as_float(v1 << 16);
            accy += __uint_as_float(v0 & 0xffff0000u) + __uint_as_float(v1 & 0xffff0000u);
            accx += __uint_as_float(v2 << 16) + __uint_as_float(v3 << 16);
            accy += __uint_as_float(v2 & 0xffff0000u) + __uint_as_float(v3 & 0xffff0000u);
        }
        for (; i < e; ++i) {
            unsigned int v0 = u1[(size_t)eidx[i] * 64 + lane];
            accx += __uint_as_float(v0 << 16);
            accy += __uint_as_float(v0 & 0xffff0000u);
        }
        float zx = accx + b1x;
        float zy = accy + b1y;
        psx += zx; pqx += zx * zx;
        psy += zy; pqy += zy * zy;
        unsigned int o = ((unsigned int)f2b(zy) << 16) | f2b(zx);
        ((unsigned int*)zb)[(size_t)node * 64 + lane] = o;
    }
    atomicAdd(&s_sum[2 * lane], psx);
    atomicAdd(&s_sum[2 * lane + 1], psy);
    atomicAdd(&s_sq[2 * lane], pqx);
    atomicAdd(&s_sq[2 * lane + 1], pqy);
    __syncthreads();
    if (tid < 128) {
        atomicAdd(&stats[tid], s_sum[tid]);
        atomicAdd(&stats[128 + tid], s_sq[tid]);
    }
}

// ---- GEMM2 fused: x = relu(BN(z)@W2+b2); if !LAST also u' = x@W1next -------
// z A-frags direct from global (BN+ReLU in regs); W2 then W1next share one LDS
// buffer (staged sequentially); x-tile round-trips through LDS for the second
// MFMA stage. LAST: write x to global (for pooling) and skip stage 2.
template <int LAST>
__global__ __launch_bounds__(256) void k_gemm2f(const unsigned short* __restrict__ zb,
                                                const unsigned short* __restrict__ Wt2,
                                                const unsigned short* __restrict__ Wt1n,
                                                const float* __restrict__ b2,
                                                const float* __restrict__ stats,
                                                const float* __restrict__ gamma,
                                                const float* __restrict__ beta,
                                                unsigned short* __restrict__ outb) {
    __shared__ unsigned short Ws[128 * 136];
    __shared__ unsigned short Xs[128 * 136];
    __shared__ float s_a[128];
    __shared__ float s_b[128];

    int tid = threadIdx.x;
    int row0 = blockIdx.x * 128;

#pragma unroll
    for (int i = 0; i < 8; ++i) {
        int chunk = tid + 256 * i;
        int n = chunk >> 4;
        int k8 = (chunk & 15) * 8;
        *(bf16x8*)&Ws[n * 136 + k8] = *(const bf16x8*)&Wt2[n * 128 + k8];
    }
    if (tid < 128) {
        float s1 = stats[tid];
        float s2 = stats[128 + tid];
        float mu = s1 / (float)N_NODES;
        float var = s2 / (float)N_NODES - mu * mu;
        float sc = rsqrtf(var + BN_EPS) * gamma[tid];
        s_a[tid] = sc;
        s_b[tid] = beta[tid] - mu * sc;
    }
    __syncthreads();

    int w = tid >> 6, lane = tid & 63, q = lane >> 4, ln = lane & 15;
    int lrbase = (w & 1) * 64, cbase = (w >> 1) * 64;

    f32x4 acc[4][4];
    f32x4 z4 = {0.f, 0.f, 0.f, 0.f};
#pragma unroll
    for (int rt = 0; rt < 4; ++rt)
#pragma unroll
        for (int ct = 0; ct < 4; ++ct) acc[rt][ct] = z4;

#pragma unroll
    for (int ks = 0; ks < 4; ++ks) {
        int ko = ks * 32 + q * 8;
        float scv[8], shv[8];
        *(float4*)&scv[0] = *(const float4*)&s_a[ko];
        *(float4*)&scv[4] = *(const float4*)&s_a[ko + 4];
        *(float4*)&shv[0] = *(const float4*)&s_b[ko];
        *(float4*)&shv[4] = *(const float4*)&s_b[ko + 4];
        bf16x8 af[4];
#pragma unroll
        for (int rt = 0; rt < 4; ++rt) {
            int row = row0 + lrbase + rt * 16 + ln;
            bf16x8 v = {0, 0, 0, 0, 0, 0, 0, 0};
            if (row < N_NODES) v = *(const bf16x8*)&zb[(size_t)row * 128 + ko];
            bf16x8 o;
#pragma unroll
            for (int t = 0; t < 8; ++t) {
                float xv = b2f((unsigned short)v[t]);
                o[t] = (short)f2b(fmaxf(xv * scv[t] + shv[t], 0.f));
            }
            af[rt] = o;
        }
        bf16x8 bfr[4];
#pragma unroll
        for (int ct = 0; ct < 4; ++ct)
            bfr[ct] = *(bf16x8*)&Ws[(cbase + ct * 16 + ln) * 136 + ko];
#pragma unroll
        for (int rt = 0; rt < 4; ++rt)
#pragma unroll
            for (int ct = 0; ct < 4; ++ct)
                acc[rt][ct] = __builtin_amdgcn_mfma_f32_16x16x32_bf16(af[rt], bfr[ct],
                                                                      acc[rt][ct], 0, 0, 0);
    }

    // x epilogue: relu(acc + b2) -> Xs (or global if LAST)
    float bsv[4];
#pragma unroll
    for (int ct = 0; ct < 4; ++ct) bsv[ct] = b2[cbase + ct * 16 + ln];
#pragma unroll
    for (int rt = 0; rt < 4; ++rt) {
        int lr0 = lrbase + rt * 16 + q * 4;
#pragma unroll
        for (int i = 0; i < 4; ++i) {
            int lr = lr0 + i;
            int gr = row0 + lr;
#pragma unroll
            for (int ct = 0; ct < 4; ++ct) {
                float xv = (gr < N_NODES) ? fmaxf(acc[rt][ct][i] + bsv[ct], 0.f) : 0.f;
                if (LAST) {
                    if (gr < N_NODES) outb[(size_t)gr * 128 + cbase + ct * 16 + ln] = f2b(xv);
                } else {
                    Xs[lr * 136 + cbase + ct * 16 + ln] = f2b(xv);
                }
            }
        }
    }

    if (!LAST) {
        __syncthreads();
#pragma unroll
        for (int i = 0; i < 8; ++i) {
            int chunk = tid + 256 * i;
            int n = chunk >> 4;
            int k8 = (chunk & 15) * 8;
            *(bf16x8*)&Ws[n * 136 + k8] = *(const bf16x8*)&Wt1n[n * 128 + k8];
        }
        __syncthreads();

#pragma unroll
        for (int rt = 0; rt < 4; ++rt)
#pragma unroll
            for (int ct = 0; ct < 4; ++ct) acc[rt][ct] = z4;

#pragma unroll
        for (int ks = 0; ks < 4; ++ks) {
            int ko = ks * 32 + q * 8;
            bf16x8 af[4], bfr[4];
#pragma unroll
            for (int rt = 0; rt < 4; ++rt)
                af[rt] = *(bf16x8*)&Xs[(lrbase + rt * 16 + ln) * 136 + ko];
#pragma unroll
            for (int ct = 0; ct < 4; ++ct)
                bfr[ct] = *(bf16x8*)&Ws[(cbase + ct * 16 + ln) * 136 + ko];
#pragma unroll
            for (int rt = 0; rt < 4; ++rt)
#pragma unroll
                for (int ct = 0; ct < 4; ++ct)
                    acc[rt][ct] = __builtin_amdgcn_mfma_f32_16x16x32_bf16(af[rt], bfr[ct],
                                                                          acc[rt][ct], 0, 0, 0);
        }
#pragma unroll
        for (int rt = 0; rt < 4; ++rt) {
            int gr0 = row0 + lrbase + rt * 16 + q * 4;
#pragma unroll
            for (int i = 0; i < 4; ++i) {
                int gr = gr0 + i;
                if (gr < N_NODES) {
#pragma unroll
                    for (int ct = 0; ct < 4; ++ct)
                        outb[(size_t)gr * 128 + cbase + ct * 16 + ln] = f2b(acc[rt][ct][i]);
                }
            }
        }
    }
}

// ---------------- graph boundaries (batch is sorted) ----------------
__global__ void k_bounds(const void* batch, const int* __restrict__ flag,
                         int* __restrict__ starts) {
    int g = blockIdx.x * 256 + threadIdx.x;
    if (g > N_GRAPHS) return;
    int f = *flag;
    int lo = 0, hi = N_NODES;
    while (lo < hi) {
        int mid = (lo + hi) >> 1;
        if (geti(batch, mid, f) < g) lo = mid + 1;
        else hi = mid;
    }
    starts[g] = lo;
}

// ---------------- global add pool (bf16 in, fp32 out) ----------------
__global__ void k_pool(const unsigned short* __restrict__ xb, const int* __restrict__ starts,
                       float* __restrict__ gp) {
    int b = blockIdx.x, fi = threadIdx.x;
    int s = starts[b], e = starts[b + 1];
    float acc = 0.f;
    for (int i = s; i < e; ++i) acc += b2f(xb[(size_t)i * 128 + fi]);
    gp[(size_t)b * 128 + fi] = acc;
}

// ---------------- head MLP ----------------
__global__ void k_head(const float* __restrict__ gp, const float* __restrict__ fW1,
                       const float* __restrict__ fb1, const float* __restrict__ fW2,
                       const float* __restrict__ fb2, float* __restrict__ out) {
    __shared__ float gs[128];
    __shared__ float hs[128];
    int b = blockIdx.x, t = threadIdx.x;
    gs[t] = gp[(size_t)b * 128 + t];
    __syncthreads();
    float a = fb1[t];
    for (int k = 0; k < 128; ++k) a += gs[k] * fW1[k * 128 + t];
    hs[t] = fmaxf(a, 0.f);
    __syncthreads();
    if (t < 64) {
        float o = fb2[t];
        for (int k = 0; k < 128; ++k) o += hs[k] * fW2[k * 64 + t];
        out[(size_t)b * 64 + t] = o;
    }
}

extern "C" void kernel_launch(void* const* d_in, const int* in_sizes, int n_in,
                              void* d_out, int out_size, void* d_ws, size_t ws_size,
                              hipStream_t stream) {
    const float* x     = (const float*)d_in[0];
    const void*  ei    = d_in[1];
    const void*  batch = d_in[2];
    const float* W1    = (const float*)d_in[3];
    const float* b1    = (const float*)d_in[4];
    const float* gamma = (const float*)d_in[5];
    const float* beta  = (const float*)d_in[6];
    const float* W2    = (const float*)d_in[7];
    const float* b2    = (const float*)d_in[8];
    const float* fW1   = (const float*)d_in[9];
    const float* fb1   = (const float*)d_in[10];
    const float* fW2   = (const float*)d_in[11];
    const float* fb2   = (const float*)d_in[12];
    float* out = (float*)d_out;

    // workspace layout (all chunks multiple of 16 B)
    unsigned short* ub = (unsigned short*)d_ws;                    // 12.8M us
    unsigned short* zb = ub + (size_t)N_NODES * D;                 // 12.8M us
    unsigned short* xb = zb + (size_t)N_NODES * D;                 // 12.8M us (final x)
    int* deg    = (int*)(xb + (size_t)N_NODES * D);                // 100,000
    int* rowp   = deg + N_NODES;                                   // 100,004 (padded)
    int* eidx   = rowp + 100004;                                   // 1,600,000
    unsigned int* tmp = (unsigned int*)(eidx + N_EDGES);           // 1,600,000
    int* starts = (int*)(tmp + N_EDGES);                           // 1,028 (padded)
    int* dflag  = starts + 1028;                                   // 4
    int* bsum   = dflag + 4;                                       // 128
    int* boff   = bsum + 128;                                      // 128
    int* gcur   = boff + 128;                                      // 512
    float* stats = (float*)(gcur + 512);                           // 768
    float* gp    = stats + NL * 256;                               // 131,072
    unsigned short* Wt = (unsigned short*)(gp + (size_t)N_GRAPHS * D);  // 6*16384 us

    hipMemsetAsync(deg, 0, N_NODES * sizeof(int), stream);
    hipMemsetAsync(stats, 0, NL * 256 * sizeof(float), stream);

    k_detect<<<1, 64, 0, stream>>>(ei, dflag);
    k_wprep<<<dim3(128, 2 * NL), 128, 0, stream>>>(W1, W2, Wt);
    k_hist<<<(N_EDGES + 255) / 256, 256, 0, stream>>>(ei, dflag, deg);
    k_scan1<<<98, 256, 0, stream>>>(deg, bsum);
    k_scan2<<<1, 64, 0, stream>>>(bsum, boff, rowp);
    k_scan3<<<98, 256, 0, stream>>>(deg, boff, rowp);
    k_gcur<<<2, 256, 0, stream>>>(rowp, gcur);
    k_part<<<(N_EDGES + EPB - 1) / EPB, 256, 0, stream>>>(ei, dflag, gcur, tmp);
    k_fscat<<<NB, 256, 0, stream>>>(tmp, rowp, eidx);

    const int gemm_grid = (N_NODES + 127) / 128;  // 782
    const int agz_grid = (N_NODES + 63) / 64;     // 1563 (4 waves x 16 nodes)

    k_gemm0<<<gemm_grid, 256, 0, stream>>>(x, Wt, ub);
    for (int l = 0; l < NL; ++l) {
        k_agz<<<agz_grid, 256, 0, stream>>>(ub, rowp, eidx, b1 + (size_t)l * D,
                                            stats + (size_t)l * 256, zb);
        if (l < NL - 1) {
            k_gemm2f<0><<<gemm_grid, 256, 0, stream>>>(
                zb, Wt + (size_t)(NL + l) * D * D, Wt + (size_t)(l + 1) * D * D,
                b2 + (size_t)l * D, stats + (size_t)l * 256,
                gamma + (size_t)l * D, beta + (size_t)l * D, ub);
        } else {
            k_gemm2f<1><<<gemm_grid, 256, 0, stream>>>(
                zb, Wt + (size_t)(NL + l) * D * D, nullptr,
                b2 + (size_t)l * D, stats + (size_t)l * 256,
                gamma + (size_t)l * D, beta + (size_t)l * D, xb);
        }
    }

    k_bounds<<<5, 256, 0, stream>>>(batch, dflag, starts);
    k_pool<<<N_GRAPHS, 128, 0, stream>>>(xb, starts, gp);
    k_head<<<N_GRAPHS, 128, 0, stream>>>(gp, fW1, fb1, fW2, fb2, out);
}

// Round 10
// 705.911 us; speedup vs baseline: 1.0599x; 1.0599x over previous
//
#include <hip/hip_runtime.h>

#define N_NODES 100000
#define N_EDGES 1600000
#define N_GRAPHS 1024
#define D 128
#define NL 3
#define BN_EPS 1e-5f
#define BG 196                                  // dst nodes per bucket
#define NB ((N_NODES + BG - 1) / BG)            // 511 buckets
#define EPB 16384                               // edges per k_part block

typedef __attribute__((ext_vector_type(8))) short bf16x8;
typedef __attribute__((ext_vector_type(4))) float f32x4;

__device__ __forceinline__ unsigned short f2b(float f) {
    unsigned int u = __float_as_uint(f);
    u += 0x7fff + ((u >> 16) & 1);   // round to nearest even
    return (unsigned short)(u >> 16);
}
__device__ __forceinline__ float b2f(unsigned short b) {
    return __uint_as_float(((unsigned int)b) << 16);
}

__device__ __forceinline__ int geti(const void* p, long long i, int f64) {
    return f64 ? (int)((const long long*)p)[i] : ((const int*)p)[i];
}

__global__ void k_detect(const void* ei, int* flag) {
    int t = threadIdx.x;
    const int* p = (const int*)ei;
    int acc = p[2 * t + 1] | p[2 * (t + 64) + 1];
    unsigned long long b = __ballot(acc != 0);
    if (t == 0) *flag = (b == 0ULL) ? 1 : 0;
}

// ---------------- weight prep: Wt[m][n][k] = bf16(W[m][k][n]) ----------------
__global__ void k_wprep(const float* __restrict__ W1, const float* __restrict__ W2,
                        unsigned short* __restrict__ Wt) {
    int m = blockIdx.y;
    int k = blockIdx.x;
    int n = threadIdx.x;
    const float* src = (m < NL) ? (W1 + (size_t)m * D * D) : (W2 + (size_t)(m - NL) * D * D);
    Wt[(size_t)m * D * D + n * D + k] = f2b(src[k * D + n]);
}

// ---------------- CSR build ----------------
__global__ void k_hist(const void* ei, const int* __restrict__ flag, int* __restrict__ deg) {
    int e = blockIdx.x * 256 + threadIdx.x;
    int f = *flag;
    if (e < N_EDGES) {
        int d = geti(ei, (long long)N_EDGES + e, f);
        atomicAdd(&deg[d], 1);
    }
}

__global__ void k_scan1(const int* __restrict__ deg, int* __restrict__ bsum) {
    __shared__ int wsum[4];
    int tid = threadIdx.x;
    int base = blockIdx.x * 1024 + tid * 4;
    int s = 0;
#pragma unroll
    for (int j = 0; j < 4; ++j) {
        int idx = base + j;
        if (idx < N_NODES) s += deg[idx];
    }
    for (int off = 32; off > 0; off >>= 1) s += __shfl_down(s, off, 64);
    if ((tid & 63) == 0) wsum[tid >> 6] = s;
    __syncthreads();
    if (tid == 0) bsum[blockIdx.x] = wsum[0] + wsum[1] + wsum[2] + wsum[3];
}

__global__ void k_scan2(const int* __restrict__ bsum, int* __restrict__ boff,
                        int* __restrict__ rowp) {
    if (threadIdx.x == 0) {
        int run = 0;
        for (int b = 0; b < 98; ++b) {
            boff[b] = run;
            run += bsum[b];
        }
        rowp[N_NODES] = run;
    }
}

__global__ void k_scan3(const int* __restrict__ deg, const int* __restrict__ boff,
                        int* __restrict__ rowp) {
    __shared__ int wsum[4];
    int tid = threadIdx.x;
    int lane = tid & 63;
    int w = tid >> 6;
    int base = blockIdx.x * 1024 + tid * 4;
    int d[4];
    int tot = 0;
#pragma unroll
    for (int j = 0; j < 4; ++j) {
        int idx = base + j;
        d[j] = (idx < N_NODES) ? deg[idx] : 0;
        tot += d[j];
    }
    int incl = tot;
    for (int off = 1; off < 64; off <<= 1) {
        int v = __shfl_up(incl, off, 64);
        if (lane >= off) incl += v;
    }
    if (lane == 63) wsum[w] = incl;
    __syncthreads();
    int woff = boff[blockIdx.x];
    for (int w2 = 0; w2 < w; ++w2) woff += wsum[w2];
    int ex = woff + incl - tot;
#pragma unroll
    for (int j = 0; j < 4; ++j) {
        int idx = base + j;
        if (idx < N_NODES) rowp[idx] = ex;
        ex += d[j];
    }
}

__global__ void k_gcur(const int* __restrict__ rowp, int* __restrict__ gcur) {
    int b = blockIdx.x * 256 + threadIdx.x;
    if (b < NB) gcur[b] = rowp[min(b * BG, N_NODES)];
}

__global__ __launch_bounds__(256) void k_part(const void* ei, const int* __restrict__ flag,
                                              int* __restrict__ gcur,
                                              unsigned int* __restrict__ tmp) {
    __shared__ int hist[NB + 1];
    __shared__ int cur[NB + 1];
    int tid = threadIdx.x;
    long long e0 = (long long)blockIdx.x * EPB;
    int f = *flag;
    for (int b = tid; b < NB; b += 256) hist[b] = 0;
    __syncthreads();
    for (int i = 0; i < EPB / 256; ++i) {
        long long e = e0 + i * 256 + tid;
        if (e < N_EDGES) {
            int d = geti(ei, (long long)N_EDGES + e, f);
            atomicAdd(&hist[d / BG], 1);
        }
    }
    __syncthreads();
    for (int b = tid; b < NB; b += 256) {
        int h = hist[b];
        cur[b] = h ? atomicAdd(&gcur[b], h) : 0;
    }
    __syncthreads();
    for (int i = 0; i < EPB / 256; ++i) {
        long long e = e0 + i * 256 + tid;
        if (e < N_EDGES) {
            int d = geti(ei, (long long)N_EDGES + e, f);
            int s = geti(ei, e, f);
            int b = d / BG;
            int pos = atomicAdd(&cur[b], 1);
            tmp[pos] = ((unsigned int)(d - b * BG) << 17) | (unsigned int)s;
        }
    }
}

__global__ __launch_bounds__(256) void k_fscat(const unsigned int* __restrict__ tmp,
                                               const int* __restrict__ rowp,
                                               int* __restrict__ eidx) {
    __shared__ int cur[BG];
    __shared__ int s_se[2];
    int b = blockIdx.x;
    int nb = b * BG;
    int nn = min(BG, N_NODES - nb);
    int tid = threadIdx.x;
    if (tid < nn) cur[tid] = rowp[nb + tid];
    if (tid == 0) s_se[0] = rowp[nb];
    if (tid == 1) s_se[1] = rowp[nb + nn];
    __syncthreads();
    for (int t = s_se[0] + tid; t < s_se[1]; t += 256) {
        unsigned int u = tmp[t];
        int dl = u >> 17;
        int pos = atomicAdd(&cur[dl], 1);
        eidx[pos] = (int)(u & 0x1FFFF);
    }
}

// ---------------- GEMM0: u0 = bf16(x) @ W1_0 (fp32 A direct, W in LDS) -------
__global__ __launch_bounds__(256) void k_gemm0(const float* __restrict__ x,
                                               const unsigned short* __restrict__ Wt,
                                               unsigned short* __restrict__ ub) {
    __shared__ unsigned short Ws[128 * 136];
    int tid = threadIdx.x;
    int row0 = blockIdx.x * 128;
#pragma unroll
    for (int i = 0; i < 8; ++i) {
        int chunk = tid + 256 * i;
        int n = chunk >> 4;
        int k8 = (chunk & 15) * 8;
        *(bf16x8*)&Ws[n * 136 + k8] = *(const bf16x8*)&Wt[n * 128 + k8];
    }
    __syncthreads();

    int w = tid >> 6, lane = tid & 63, q = lane >> 4, ln = lane & 15;
    int rbase = row0 + (w & 1) * 64, cbase = (w >> 1) * 64;

    f32x4 acc[4][4];
    f32x4 z4 = {0.f, 0.f, 0.f, 0.f};
#pragma unroll
    for (int rt = 0; rt < 4; ++rt)
#pragma unroll
        for (int ct = 0; ct < 4; ++ct) acc[rt][ct] = z4;

#pragma unroll
    for (int ks = 0; ks < 4; ++ks) {
        int ko = ks * 32 + q * 8;
        bf16x8 af[4];
#pragma unroll
        for (int rt = 0; rt < 4; ++rt) {
            int row = rbase + rt * 16 + ln;
            bf16x8 v = {0, 0, 0, 0, 0, 0, 0, 0};
            if (row < N_NODES) {
                float4 p0 = *(const float4*)&x[(size_t)row * 128 + ko];
                float4 p1 = *(const float4*)&x[(size_t)row * 128 + ko + 4];
                v[0] = (short)f2b(p0.x); v[1] = (short)f2b(p0.y);
                v[2] = (short)f2b(p0.z); v[3] = (short)f2b(p0.w);
                v[4] = (short)f2b(p1.x); v[5] = (short)f2b(p1.y);
                v[6] = (short)f2b(p1.z); v[7] = (short)f2b(p1.w);
            }
            af[rt] = v;
        }
        bf16x8 bfr[4];
#pragma unroll
        for (int ct = 0; ct < 4; ++ct)
            bfr[ct] = *(bf16x8*)&Ws[(cbase + ct * 16 + ln) * 136 + ko];
#pragma unroll
        for (int rt = 0; rt < 4; ++rt)
#pragma unroll
            for (int ct = 0; ct < 4; ++ct)
                acc[rt][ct] = __builtin_amdgcn_mfma_f32_16x16x32_bf16(af[rt], bfr[ct],
                                                                      acc[rt][ct], 0, 0, 0);
    }
#pragma unroll
    for (int rt = 0; rt < 4; ++rt) {
        int gr0 = rbase + rt * 16 + q * 4;
#pragma unroll
        for (int i = 0; i < 4; ++i) {
            int gr = gr0 + i;
            if (gr < N_NODES) {
#pragma unroll
                for (int ct = 0; ct < 4; ++ct)
                    ub[(size_t)gr * 128 + cbase + ct * 16 + ln] = f2b(acc[rt][ct][i]);
            }
        }
    }
}

// ---- aggregation in u-space: z = u_i + sum_j u_j (b1 dropped: BN-invariant) --
// One wave per node, high occupancy, no LDS, no stats.
__global__ void k_agz(const unsigned short* __restrict__ ub, const int* __restrict__ rowp,
                      const int* __restrict__ eidx, unsigned short* __restrict__ zb) {
    int wid = threadIdx.x >> 6;
    int lane = threadIdx.x & 63;
    int node = blockIdx.x * 4 + wid;
    const unsigned int* u1 = (const unsigned int*)ub;   // 64 dwords per row
    unsigned int u = u1[(size_t)node * 64 + lane];
    float accx = __uint_as_float(u << 16);
    float accy = __uint_as_float(u & 0xffff0000u);
    int s = rowp[node], e = rowp[node + 1];
    int i = s;
    for (; i + 3 < e; i += 4) {
        unsigned int v0 = u1[(size_t)eidx[i] * 64 + lane];
        unsigned int v1 = u1[(size_t)eidx[i + 1] * 64 + lane];
        unsigned int v2 = u1[(size_t)eidx[i + 2] * 64 + lane];
        unsigned int v3 = u1[(size_t)eidx[i + 3] * 64 + lane];
        accx += __uint_as_float(v0 << 16) + __uint_as_float(v1 << 16);
        accy += __uint_as_float(v0 & 0xffff0000u) + __uint_as_float(v1 & 0xffff0000u);
        accx += __uint_as_float(v2 << 16) + __uint_as_float(v3 << 16);
        accy += __uint_as_float(v2 & 0xffff0000u) + __uint_as_float(v3 & 0xffff0000u);
    }
    for (; i < e; ++i) {
        unsigned int v0 = u1[(size_t)eidx[i] * 64 + lane];
        accx += __uint_as_float(v0 << 16);
        accy += __uint_as_float(v0 & 0xffff0000u);
    }
    unsigned int o = ((unsigned int)f2b(accy) << 16) | f2b(accx);
    ((unsigned int*)zb)[(size_t)node * 64 + lane] = o;
}

// ---- per-feature sum/sumsq over zb (streaming, two-level reduction) ---------
__global__ __launch_bounds__(256) void k_zstats(const unsigned short* __restrict__ zb,
                                                float* __restrict__ stats) {
    __shared__ float s_sum[128];
    __shared__ float s_sq[128];
    int tid = threadIdx.x;
    if (tid < 128) {
        s_sum[tid] = 0.f;
        s_sq[tid] = 0.f;
    }
    __syncthreads();
    int lane = tid & 63, w = tid >> 6;
    const unsigned int* z1 = (const unsigned int*)zb;
    float psx = 0.f, psy = 0.f, pqx = 0.f, pqy = 0.f;
    const int R = (N_NODES + 255) / 256;    // rows per block (ceil)
    int row0 = blockIdx.x * R;
    int row1 = min(row0 + R, N_NODES);
    for (int row = row0 + w; row < row1; row += 4) {
        unsigned int v = z1[(size_t)row * 64 + lane];
        float zx = __uint_as_float(v << 16);
        float zy = __uint_as_float(v & 0xffff0000u);
        psx += zx; pqx += zx * zx;
        psy += zy; pqy += zy * zy;
    }
    atomicAdd(&s_sum[2 * lane], psx);
    atomicAdd(&s_sum[2 * lane + 1], psy);
    atomicAdd(&s_sq[2 * lane], pqx);
    atomicAdd(&s_sq[2 * lane + 1], pqy);
    __syncthreads();
    if (tid < 128) {
        atomicAdd(&stats[tid], s_sum[tid]);
        atomicAdd(&stats[128 + tid], s_sq[tid]);
    }
}

// ---- GEMM2 fused: x = relu(BN(z)@W2+b2); if !LAST also u' = x@W1next -------
template <int LAST>
__global__ __launch_bounds__(256) void k_gemm2f(const unsigned short* __restrict__ zb,
                                                const unsigned short* __restrict__ Wt2,
                                                const unsigned short* __restrict__ Wt1n,
                                                const float* __restrict__ b2,
                                                const float* __restrict__ stats,
                                                const float* __restrict__ gamma,
                                                const float* __restrict__ beta,
                                                unsigned short* __restrict__ outb) {
    __shared__ unsigned short Ws[128 * 136];
    __shared__ unsigned short Xs[128 * 136];
    __shared__ float s_a[128];
    __shared__ float s_b[128];

    int tid = threadIdx.x;
    int row0 = blockIdx.x * 128;

#pragma unroll
    for (int i = 0; i < 8; ++i) {
        int chunk = tid + 256 * i;
        int n = chunk >> 4;
        int k8 = (chunk & 15) * 8;
        *(bf16x8*)&Ws[n * 136 + k8] = *(const bf16x8*)&Wt2[n * 128 + k8];
    }
    if (tid < 128) {
        float s1 = stats[tid];
        float s2 = stats[128 + tid];
        float mu = s1 / (float)N_NODES;
        float var = s2 / (float)N_NODES - mu * mu;
        float sc = rsqrtf(var + BN_EPS) * gamma[tid];
        s_a[tid] = sc;
        s_b[tid] = beta[tid] - mu * sc;
    }
    __syncthreads();

    int w = tid >> 6, lane = tid & 63, q = lane >> 4, ln = lane & 15;
    int lrbase = (w & 1) * 64, cbase = (w >> 1) * 64;

    f32x4 acc[4][4];
    f32x4 z4 = {0.f, 0.f, 0.f, 0.f};
#pragma unroll
    for (int rt = 0; rt < 4; ++rt)
#pragma unroll
        for (int ct = 0; ct < 4; ++ct) acc[rt][ct] = z4;

#pragma unroll
    for (int ks = 0; ks < 4; ++ks) {
        int ko = ks * 32 + q * 8;
        float scv[8], shv[8];
        *(float4*)&scv[0] = *(const float4*)&s_a[ko];
        *(float4*)&scv[4] = *(const float4*)&s_a[ko + 4];
        *(float4*)&shv[0] = *(const float4*)&s_b[ko];
        *(float4*)&shv[4] = *(const float4*)&s_b[ko + 4];
        bf16x8 af[4];
#pragma unroll
        for (int rt = 0; rt < 4; ++rt) {
            int row = row0 + lrbase + rt * 16 + ln;
            bf16x8 v = {0, 0, 0, 0, 0, 0, 0, 0};
            if (row < N_NODES) v = *(const bf16x8*)&zb[(size_t)row * 128 + ko];
            bf16x8 o;
#pragma unroll
            for (int t = 0; t < 8; ++t) {
                float xv = b2f((unsigned short)v[t]);
                o[t] = (short)f2b(fmaxf(xv * scv[t] + shv[t], 0.f));
            }
            af[rt] = o;
        }
        bf16x8 bfr[4];
#pragma unroll
        for (int ct = 0; ct < 4; ++ct)
            bfr[ct] = *(bf16x8*)&Ws[(cbase + ct * 16 + ln) * 136 + ko];
#pragma unroll
        for (int rt = 0; rt < 4; ++rt)
#pragma unroll
            for (int ct = 0; ct < 4; ++ct)
                acc[rt][ct] = __builtin_amdgcn_mfma_f32_16x16x32_bf16(af[rt], bfr[ct],
                                                                      acc[rt][ct], 0, 0, 0);
    }

    // x epilogue: relu(acc + b2) -> Xs (or global if LAST)
    float bsv[4];
#pragma unroll
    for (int ct = 0; ct < 4; ++ct) bsv[ct] = b2[cbase + ct * 16 + ln];
#pragma unroll
    for (int rt = 0; rt < 4; ++rt) {
        int lr0 = lrbase + rt * 16 + q * 4;
#pragma unroll
        for (int i = 0; i < 4; ++i) {
            int lr = lr0 + i;
            int gr = row0 + lr;
#pragma unroll
            for (int ct = 0; ct < 4; ++ct) {
                float xv = (gr < N_NODES) ? fmaxf(acc[rt][ct][i] + bsv[ct], 0.f) : 0.f;
                if (LAST) {
                    if (gr < N_NODES) outb[(size_t)gr * 128 + cbase + ct * 16 + ln] = f2b(xv);
                } else {
                    Xs[lr * 136 + cbase + ct * 16 + ln] = f2b(xv);
                }
            }
        }
    }

    if (!LAST) {
        __syncthreads();
#pragma unroll
        for (int i = 0; i < 8; ++i) {
            int chunk = tid + 256 * i;
            int n = chunk >> 4;
            int k8 = (chunk & 15) * 8;
            *(bf16x8*)&Ws[n * 136 + k8] = *(const bf16x8*)&Wt1n[n * 128 + k8];
        }
        __syncthreads();

#pragma unroll
        for (int rt = 0; rt < 4; ++rt)
#pragma unroll
            for (int ct = 0; ct < 4; ++ct) acc[rt][ct] = z4;

#pragma unroll
        for (int ks = 0; ks < 4; ++ks) {
            int ko = ks * 32 + q * 8;
            bf16x8 af[4], bfr[4];
#pragma unroll
            for (int rt = 0; rt < 4; ++rt)
                af[rt] = *(bf16x8*)&Xs[(lrbase + rt * 16 + ln) * 136 + ko];
#pragma unroll
            for (int ct = 0; ct < 4; ++ct)
                bfr[ct] = *(bf16x8*)&Ws[(cbase + ct * 16 + ln) * 136 + ko];
#pragma unroll
            for (int rt = 0; rt < 4; ++rt)
#pragma unroll
                for (int ct = 0; ct < 4; ++ct)
                    acc[rt][ct] = __builtin_amdgcn_mfma_f32_16x16x32_bf16(af[rt], bfr[ct],
                                                                          acc[rt][ct], 0, 0, 0);
        }
#pragma unroll
        for (int rt = 0; rt < 4; ++rt) {
            int gr0 = row0 + lrbase + rt * 16 + q * 4;
#pragma unroll
            for (int i = 0; i < 4; ++i) {
                int gr = gr0 + i;
                if (gr < N_NODES) {
#pragma unroll
                    for (int ct = 0; ct < 4; ++ct)
                        outb[(size_t)gr * 128 + cbase + ct * 16 + ln] = f2b(acc[rt][ct][i]);
                }
            }
        }
    }
}

// ---------------- graph boundaries (batch is sorted) ----------------
__global__ void k_bounds(const void* batch, const int* __restrict__ flag,
                         int* __restrict__ starts) {
    int g = blockIdx.x * 256 + threadIdx.x;
    if (g > N_GRAPHS) return;
    int f = *flag;
    int lo = 0, hi = N_NODES;
    while (lo < hi) {
        int mid = (lo + hi) >> 1;
        if (geti(batch, mid, f) < g) lo = mid + 1;
        else hi = mid;
    }
    starts[g] = lo;
}

// ---------------- global add pool (bf16 in, fp32 out) ----------------
__global__ void k_pool(const unsigned short* __restrict__ xb, const int* __restrict__ starts,
                       float* __restrict__ gp) {
    int b = blockIdx.x, fi = threadIdx.x;
    int s = starts[b], e = starts[b + 1];
    float acc = 0.f;
    for (int i = s; i < e; ++i) acc += b2f(xb[(size_t)i * 128 + fi]);
    gp[(size_t)b * 128 + fi] = acc;
}

// ---------------- head MLP ----------------
__global__ void k_head(const float* __restrict__ gp, const float* __restrict__ fW1,
                       const float* __restrict__ fb1, const float* __restrict__ fW2,
                       const float* __restrict__ fb2, float* __restrict__ out) {
    __shared__ float gs[128];
    __shared__ float hs[128];
    int b = blockIdx.x, t = threadIdx.x;
    gs[t] = gp[(size_t)b * 128 + t];
    __syncthreads();
    float a = fb1[t];
    for (int k = 0; k < 128; ++k) a += gs[k] * fW1[k * 128 + t];
    hs[t] = fmaxf(a, 0.f);
    __syncthreads();
    if (t < 64) {
        float o = fb2[t];
        for (int k = 0; k < 128; ++k) o += hs[k] * fW2[k * 64 + t];
        out[(size_t)b * 64 + t] = o;
    }
}

extern "C" void kernel_launch(void* const* d_in, const int* in_sizes, int n_in,
                              void* d_out, int out_size, void* d_ws, size_t ws_size,
                              hipStream_t stream) {
    const float* x     = (const float*)d_in[0];
    const void*  ei    = d_in[1];
    const void*  batch = d_in[2];
    const float* W1    = (const float*)d_in[3];
    const float* gamma = (const float*)d_in[5];
    const float* beta  = (const float*)d_in[6];
    const float* W2    = (const float*)d_in[7];
    const float* b2    = (const float*)d_in[8];
    const float* fW1   = (const float*)d_in[9];
    const float* fb1   = (const float*)d_in[10];
    const float* fW2   = (const float*)d_in[11];
    const float* fb2   = (const float*)d_in[12];
    float* out = (float*)d_out;

    // workspace layout (all chunks multiple of 16 B)
    unsigned short* ub = (unsigned short*)d_ws;                    // 12.8M us
    unsigned short* zb = ub + (size_t)N_NODES * D;                 // 12.8M us
    unsigned short* xb = zb + (size_t)N_NODES * D;                 // 12.8M us (final x)
    int* deg    = (int*)(xb + (size_t)N_NODES * D);                // 100,000
    int* rowp   = deg + N_NODES;                                   // 100,004 (padded)
    int* eidx   = rowp + 100004;                                   // 1,600,000
    unsigned int* tmp = (unsigned int*)(eidx + N_EDGES);           // 1,600,000
    int* starts = (int*)(tmp + N_EDGES);                           // 1,028 (padded)
    int* dflag  = starts + 1028;                                   // 4
    int* bsum   = dflag + 4;                                       // 128
    int* boff   = bsum + 128;                                      // 128
    int* gcur   = boff + 128;                                      // 512
    float* stats = (float*)(gcur + 512);                           // 768
    float* gp    = stats + NL * 256;                               // 131,072
    unsigned short* Wt = (unsigned short*)(gp + (size_t)N_GRAPHS * D);  // 6*16384 us

    hipMemsetAsync(deg, 0, N_NODES * sizeof(int), stream);
    hipMemsetAsync(stats, 0, NL * 256 * sizeof(float), stream);

    k_detect<<<1, 64, 0, stream>>>(ei, dflag);
    k_wprep<<<dim3(128, 2 * NL), 128, 0, stream>>>(W1, W2, Wt);
    k_hist<<<(N_EDGES + 255) / 256, 256, 0, stream>>>(ei, dflag, deg);
    k_scan1<<<98, 256, 0, stream>>>(deg, bsum);
    k_scan2<<<1, 64, 0, stream>>>(bsum, boff, rowp);
    k_scan3<<<98, 256, 0, stream>>>(deg, boff, rowp);
    k_gcur<<<2, 256, 0, stream>>>(rowp, gcur);
    k_part<<<(N_EDGES + EPB - 1) / EPB, 256, 0, stream>>>(ei, dflag, gcur, tmp);
    k_fscat<<<NB, 256, 0, stream>>>(tmp, rowp, eidx);

    const int gemm_grid = (N_NODES + 127) / 128;  // 782

    k_gemm0<<<gemm_grid, 256, 0, stream>>>(x, Wt, ub);
    for (int l = 0; l < NL; ++l) {
        k_agz<<<N_NODES / 4, 256, 0, stream>>>(ub, rowp, eidx, zb);
        k_zstats<<<256, 256, 0, stream>>>(zb, stats + (size_t)l * 256);
        if (l < NL - 1) {
            k_gemm2f<0><<<gemm_grid, 256, 0, stream>>>(
                zb, Wt + (size_t)(NL + l) * D * D, Wt + (size_t)(l + 1) * D * D,
                b2 + (size_t)l * D, stats + (size_t)l * 256,
                gamma + (size_t)l * D, beta + (size_t)l * D, ub);
        } else {
            k_gemm2f<1><<<gemm_grid, 256, 0, stream>>>(
                zb, Wt + (size_t)(NL + l) * D * D, nullptr,
                b2 + (size_t)l * D, stats + (size_t)l * 256,
                gamma + (size_t)l * D, beta + (size_t)l * D, xb);
        }
    }

    k_bounds<<<5, 256, 0, stream>>>(batch, dflag, starts);
    k_pool<<<N_GRAPHS, 128, 0, stream>>>(xb, starts, gp);
    k_head<<<N_GRAPHS, 128, 0, stream>>>(gp, fW1, fb1, fW2, fb2, out);
}

// Round 11
// 660.587 us; speedup vs baseline: 1.1326x; 1.0686x over previous
//
#include <hip/hip_runtime.h>

#define N_NODES 100000
#define N_EDGES 1600000
#define N_GRAPHS 1024
#define D 128
#define NL 3
#define BN_EPS 1e-5f
#define BG 196                                  // dst nodes per bucket
#define NB ((N_NODES + BG - 1) / BG)            // 511 buckets
#define EPB 16384                               // edges per k_part block

typedef __attribute__((ext_vector_type(8))) short bf16x8;
typedef __attribute__((ext_vector_type(4))) float f32x4;

__device__ __forceinline__ unsigned short f2b(float f) {
    unsigned int u = __float_as_uint(f);
    u += 0x7fff + ((u >> 16) & 1);   // round to nearest even
    return (unsigned short)(u >> 16);
}
__device__ __forceinline__ float b2f(unsigned short b) {
    return __uint_as_float(((unsigned int)b) << 16);
}

__device__ __forceinline__ int geti(const void* p, long long i, int f64) {
    return f64 ? (int)((const long long*)p)[i] : ((const int*)p)[i];
}

// ------- weight prep: Wt[m][n][k] = bf16(W[m][k][n]); block(0,0) also detects
// the edge-index dtype (int64 vs int32) into *flag.
__global__ void k_wprep(const float* __restrict__ W1, const float* __restrict__ W2,
                        unsigned short* __restrict__ Wt, const void* ei, int* flag) {
    int m = blockIdx.y;
    int k = blockIdx.x;
    int n = threadIdx.x;
    const float* src = (m < NL) ? (W1 + (size_t)m * D * D) : (W2 + (size_t)(m - NL) * D * D);
    Wt[(size_t)m * D * D + n * D + k] = f2b(src[k * D + n]);
    if (blockIdx.x == 0 && blockIdx.y == 0 && threadIdx.x < 64) {
        int t = threadIdx.x;
        const int* p = (const int*)ei;
        int acc = p[2 * t + 1] | p[2 * (t + 64) + 1];
        unsigned long long b = __ballot(acc != 0);
        if (t == 0) *flag = (b == 0ULL) ? 1 : 0;
    }
}

// ---------------- CSR build ----------------
__global__ void k_hist(const void* ei, const int* __restrict__ flag, int* __restrict__ deg) {
    int e = blockIdx.x * 256 + threadIdx.x;
    int f = *flag;
    if (e < N_EDGES) {
        int d = geti(ei, (long long)N_EDGES + e, f);
        atomicAdd(&deg[d], 1);
    }
}

__global__ void k_scan1(const int* __restrict__ deg, int* __restrict__ bsum) {
    __shared__ int wsum[4];
    int tid = threadIdx.x;
    int base = blockIdx.x * 1024 + tid * 4;
    int s = 0;
#pragma unroll
    for (int j = 0; j < 4; ++j) {
        int idx = base + j;
        if (idx < N_NODES) s += deg[idx];
    }
    for (int off = 32; off > 0; off >>= 1) s += __shfl_down(s, off, 64);
    if ((tid & 63) == 0) wsum[tid >> 6] = s;
    __syncthreads();
    if (tid == 0) bsum[blockIdx.x] = wsum[0] + wsum[1] + wsum[2] + wsum[3];
}

__global__ void k_scan2(const int* __restrict__ bsum, int* __restrict__ boff,
                        int* __restrict__ rowp) {
    if (threadIdx.x == 0) {
        int run = 0;
        for (int b = 0; b < 98; ++b) {
            boff[b] = run;
            run += bsum[b];
        }
        rowp[N_NODES] = run;
    }
}

// also emits gcur[b] = rowp[b*BG] (bucket-start cursors for k_part)
__global__ void k_scan3(const int* __restrict__ deg, const int* __restrict__ boff,
                        int* __restrict__ rowp, int* __restrict__ gcur) {
    __shared__ int wsum[4];
    int tid = threadIdx.x;
    int lane = tid & 63;
    int w = tid >> 6;
    int base = blockIdx.x * 1024 + tid * 4;
    int d[4];
    int tot = 0;
#pragma unroll
    for (int j = 0; j < 4; ++j) {
        int idx = base + j;
        d[j] = (idx < N_NODES) ? deg[idx] : 0;
        tot += d[j];
    }
    int incl = tot;
    for (int off = 1; off < 64; off <<= 1) {
        int v = __shfl_up(incl, off, 64);
        if (lane >= off) incl += v;
    }
    if (lane == 63) wsum[w] = incl;
    __syncthreads();
    int woff = boff[blockIdx.x];
    for (int w2 = 0; w2 < w; ++w2) woff += wsum[w2];
    int ex = woff + incl - tot;
#pragma unroll
    for (int j = 0; j < 4; ++j) {
        int idx = base + j;
        if (idx < N_NODES) {
            rowp[idx] = ex;
            if (idx % BG == 0) gcur[idx / BG] = ex;
        }
        ex += d[j];
    }
}

__global__ __launch_bounds__(256) void k_part(const void* ei, const int* __restrict__ flag,
                                              int* __restrict__ gcur,
                                              unsigned int* __restrict__ tmp) {
    __shared__ int hist[NB + 1];
    __shared__ int cur[NB + 1];
    int tid = threadIdx.x;
    long long e0 = (long long)blockIdx.x * EPB;
    int f = *flag;
    for (int b = tid; b < NB; b += 256) hist[b] = 0;
    __syncthreads();
    for (int i = 0; i < EPB / 256; ++i) {
        long long e = e0 + i * 256 + tid;
        if (e < N_EDGES) {
            int d = geti(ei, (long long)N_EDGES + e, f);
            atomicAdd(&hist[d / BG], 1);
        }
    }
    __syncthreads();
    for (int b = tid; b < NB; b += 256) {
        int h = hist[b];
        cur[b] = h ? atomicAdd(&gcur[b], h) : 0;
    }
    __syncthreads();
    for (int i = 0; i < EPB / 256; ++i) {
        long long e = e0 + i * 256 + tid;
        if (e < N_EDGES) {
            int d = geti(ei, (long long)N_EDGES + e, f);
            int s = geti(ei, e, f);
            int b = d / BG;
            int pos = atomicAdd(&cur[b], 1);
            tmp[pos] = ((unsigned int)(d - b * BG) << 17) | (unsigned int)s;
        }
    }
}

__global__ __launch_bounds__(256) void k_fscat(const unsigned int* __restrict__ tmp,
                                               const int* __restrict__ rowp,
                                               int* __restrict__ eidx) {
    __shared__ int cur[BG];
    __shared__ int s_se[2];
    int b = blockIdx.x;
    int nb = b * BG;
    int nn = min(BG, N_NODES - nb);
    int tid = threadIdx.x;
    if (tid < nn) cur[tid] = rowp[nb + tid];
    if (tid == 0) s_se[0] = rowp[nb];
    if (tid == 1) s_se[1] = rowp[nb + nn];
    __syncthreads();
    for (int t = s_se[0] + tid; t < s_se[1]; t += 256) {
        unsigned int u = tmp[t];
        int dl = u >> 17;
        int pos = atomicAdd(&cur[dl], 1);
        eidx[pos] = (int)(u & 0x1FFFF);
    }
}

// ---------------- GEMM0: u0 = bf16(x) @ W1_0 (fp32 A direct, W in LDS) -------
__global__ __launch_bounds__(256) void k_gemm0(const float* __restrict__ x,
                                               const unsigned short* __restrict__ Wt,
                                               unsigned short* __restrict__ ub) {
    __shared__ unsigned short Ws[128 * 136];
    int tid = threadIdx.x;
    int row0 = blockIdx.x * 128;
#pragma unroll
    for (int i = 0; i < 8; ++i) {
        int chunk = tid + 256 * i;
        int n = chunk >> 4;
        int k8 = (chunk & 15) * 8;
        *(bf16x8*)&Ws[n * 136 + k8] = *(const bf16x8*)&Wt[n * 128 + k8];
    }
    __syncthreads();

    int w = tid >> 6, lane = tid & 63, q = lane >> 4, ln = lane & 15;
    int rbase = row0 + (w & 1) * 64, cbase = (w >> 1) * 64;

    f32x4 acc[4][4];
    f32x4 z4 = {0.f, 0.f, 0.f, 0.f};
#pragma unroll
    for (int rt = 0; rt < 4; ++rt)
#pragma unroll
        for (int ct = 0; ct < 4; ++ct) acc[rt][ct] = z4;

#pragma unroll
    for (int ks = 0; ks < 4; ++ks) {
        int ko = ks * 32 + q * 8;
        bf16x8 af[4];
#pragma unroll
        for (int rt = 0; rt < 4; ++rt) {
            int row = rbase + rt * 16 + ln;
            bf16x8 v = {0, 0, 0, 0, 0, 0, 0, 0};
            if (row < N_NODES) {
                float4 p0 = *(const float4*)&x[(size_t)row * 128 + ko];
                float4 p1 = *(const float4*)&x[(size_t)row * 128 + ko + 4];
                v[0] = (short)f2b(p0.x); v[1] = (short)f2b(p0.y);
                v[2] = (short)f2b(p0.z); v[3] = (short)f2b(p0.w);
                v[4] = (short)f2b(p1.x); v[5] = (short)f2b(p1.y);
                v[6] = (short)f2b(p1.z); v[7] = (short)f2b(p1.w);
            }
            af[rt] = v;
        }
        bf16x8 bfr[4];
#pragma unroll
        for (int ct = 0; ct < 4; ++ct)
            bfr[ct] = *(bf16x8*)&Ws[(cbase + ct * 16 + ln) * 136 + ko];
#pragma unroll
        for (int rt = 0; rt < 4; ++rt)
#pragma unroll
            for (int ct = 0; ct < 4; ++ct)
                acc[rt][ct] = __builtin_amdgcn_mfma_f32_16x16x32_bf16(af[rt], bfr[ct],
                                                                      acc[rt][ct], 0, 0, 0);
    }
#pragma unroll
    for (int rt = 0; rt < 4; ++rt) {
        int gr0 = rbase + rt * 16 + q * 4;
#pragma unroll
        for (int i = 0; i < 4; ++i) {
            int gr = gr0 + i;
            if (gr < N_NODES) {
#pragma unroll
                for (int ct = 0; ct < 4; ++ct)
                    ub[(size_t)gr * 128 + cbase + ct * 16 + ln] = f2b(acc[rt][ct][i]);
            }
        }
    }
}

// ---- aggregation in u-space: z = u_i + sum_j u_j (b1 dropped: BN-invariant) --
// One wave per node, high occupancy, no LDS; unroll 8 for deep MLP.
__global__ void k_agz(const unsigned short* __restrict__ ub, const int* __restrict__ rowp,
                      const int* __restrict__ eidx, unsigned short* __restrict__ zb) {
    int wid = threadIdx.x >> 6;
    int lane = threadIdx.x & 63;
    int node = blockIdx.x * 4 + wid;
    const unsigned int* u1 = (const unsigned int*)ub;   // 64 dwords per row
    unsigned int u = u1[(size_t)node * 64 + lane];
    float accx = __uint_as_float(u << 16);
    float accy = __uint_as_float(u & 0xffff0000u);
    int s = rowp[node], e = rowp[node + 1];
    int i = s;
    for (; i + 7 < e; i += 8) {
        unsigned int v0 = u1[(size_t)eidx[i] * 64 + lane];
        unsigned int v1 = u1[(size_t)eidx[i + 1] * 64 + lane];
        unsigned int v2 = u1[(size_t)eidx[i + 2] * 64 + lane];
        unsigned int v3 = u1[(size_t)eidx[i + 3] * 64 + lane];
        unsigned int v4 = u1[(size_t)eidx[i + 4] * 64 + lane];
        unsigned int v5 = u1[(size_t)eidx[i + 5] * 64 + lane];
        unsigned int v6 = u1[(size_t)eidx[i + 6] * 64 + lane];
        unsigned int v7 = u1[(size_t)eidx[i + 7] * 64 + lane];
        accx += __uint_as_float(v0 << 16) + __uint_as_float(v1 << 16) +
                __uint_as_float(v2 << 16) + __uint_as_float(v3 << 16) +
                __uint_as_float(v4 << 16) + __uint_as_float(v5 << 16) +
                __uint_as_float(v6 << 16) + __uint_as_float(v7 << 16);
        accy += __uint_as_float(v0 & 0xffff0000u) + __uint_as_float(v1 & 0xffff0000u) +
                __uint_as_float(v2 & 0xffff0000u) + __uint_as_float(v3 & 0xffff0000u) +
                __uint_as_float(v4 & 0xffff0000u) + __uint_as_float(v5 & 0xffff0000u) +
                __uint_as_float(v6 & 0xffff0000u) + __uint_as_float(v7 & 0xffff0000u);
    }
    for (; i + 1 < e; i += 2) {
        unsigned int v0 = u1[(size_t)eidx[i] * 64 + lane];
        unsigned int v1 = u1[(size_t)eidx[i + 1] * 64 + lane];
        accx += __uint_as_float(v0 << 16) + __uint_as_float(v1 << 16);
        accy += __uint_as_float(v0 & 0xffff0000u) + __uint_as_float(v1 & 0xffff0000u);
    }
    if (i < e) {
        unsigned int v0 = u1[(size_t)eidx[i] * 64 + lane];
        accx += __uint_as_float(v0 << 16);
        accy += __uint_as_float(v0 & 0xffff0000u);
    }
    unsigned int o = ((unsigned int)f2b(accy) << 16) | f2b(accx);
    ((unsigned int*)zb)[(size_t)node * 64 + lane] = o;
}

// ---- per-feature sum/sumsq over zb (streaming, two-level reduction) ---------
__global__ __launch_bounds__(256) void k_zstats(const unsigned short* __restrict__ zb,
                                                float* __restrict__ stats) {
    __shared__ float s_sum[128];
    __shared__ float s_sq[128];
    int tid = threadIdx.x;
    if (tid < 128) {
        s_sum[tid] = 0.f;
        s_sq[tid] = 0.f;
    }
    __syncthreads();
    int lane = tid & 63, w = tid >> 6;
    const unsigned int* z1 = (const unsigned int*)zb;
    float psx = 0.f, psy = 0.f, pqx = 0.f, pqy = 0.f;
    const int R = (N_NODES + 255) / 256;    // rows per block (ceil)
    int row0 = blockIdx.x * R;
    int row1 = min(row0 + R, N_NODES);
    for (int row = row0 + w; row < row1; row += 4) {
        unsigned int v = z1[(size_t)row * 64 + lane];
        float zx = __uint_as_float(v << 16);
        float zy = __uint_as_float(v & 0xffff0000u);
        psx += zx; pqx += zx * zx;
        psy += zy; pqy += zy * zy;
    }
    atomicAdd(&s_sum[2 * lane], psx);
    atomicAdd(&s_sum[2 * lane + 1], psy);
    atomicAdd(&s_sq[2 * lane], pqx);
    atomicAdd(&s_sq[2 * lane + 1], pqy);
    __syncthreads();
    if (tid < 128) {
        atomicAdd(&stats[tid], s_sum[tid]);
        atomicAdd(&stats[128 + tid], s_sq[tid]);
    }
}

// ---- GEMM2 fused: x = relu(BN(z)@W2+b2); if !LAST also u' = x@W1next -------
template <int LAST>
__global__ __launch_bounds__(256) void k_gemm2f(const unsigned short* __restrict__ zb,
                                                const unsigned short* __restrict__ Wt2,
                                                const unsigned short* __restrict__ Wt1n,
                                                const float* __restrict__ b2,
                                                const float* __restrict__ stats,
                                                const float* __restrict__ gamma,
                                                const float* __restrict__ beta,
                                                unsigned short* __restrict__ outb) {
    __shared__ unsigned short Ws[128 * 136];
    __shared__ unsigned short Xs[128 * 136];
    __shared__ float s_a[128];
    __shared__ float s_b[128];

    int tid = threadIdx.x;
    int row0 = blockIdx.x * 128;

#pragma unroll
    for (int i = 0; i < 8; ++i) {
        int chunk = tid + 256 * i;
        int n = chunk >> 4;
        int k8 = (chunk & 15) * 8;
        *(bf16x8*)&Ws[n * 136 + k8] = *(const bf16x8*)&Wt2[n * 128 + k8];
    }
    if (tid < 128) {
        float s1 = stats[tid];
        float s2 = stats[128 + tid];
        float mu = s1 / (float)N_NODES;
        float var = s2 / (float)N_NODES - mu * mu;
        float sc = rsqrtf(var + BN_EPS) * gamma[tid];
        s_a[tid] = sc;
        s_b[tid] = beta[tid] - mu * sc;
    }
    __syncthreads();

    int w = tid >> 6, lane = tid & 63, q = lane >> 4, ln = lane & 15;
    int lrbase = (w & 1) * 64, cbase = (w >> 1) * 64;

    f32x4 acc[4][4];
    f32x4 z4 = {0.f, 0.f, 0.f, 0.f};
#pragma unroll
    for (int rt = 0; rt < 4; ++rt)
#pragma unroll
        for (int ct = 0; ct < 4; ++ct) acc[rt][ct] = z4;

#pragma unroll
    for (int ks = 0; ks < 4; ++ks) {
        int ko = ks * 32 + q * 8;
        float scv[8], shv[8];
        *(float4*)&scv[0] = *(const float4*)&s_a[ko];
        *(float4*)&scv[4] = *(const float4*)&s_a[ko + 4];
        *(float4*)&shv[0] = *(const float4*)&s_b[ko];
        *(float4*)&shv[4] = *(const float4*)&s_b[ko + 4];
        bf16x8 af[4];
#pragma unroll
        for (int rt = 0; rt < 4; ++rt) {
            int row = row0 + lrbase + rt * 16 + ln;
            bf16x8 v = {0, 0, 0, 0, 0, 0, 0, 0};
            if (row < N_NODES) v = *(const bf16x8*)&zb[(size_t)row * 128 + ko];
            bf16x8 o;
#pragma unroll
            for (int t = 0; t < 8; ++t) {
                float xv = b2f((unsigned short)v[t]);
                o[t] = (short)f2b(fmaxf(xv * scv[t] + shv[t], 0.f));
            }
            af[rt] = o;
        }
        bf16x8 bfr[4];
#pragma unroll
        for (int ct = 0; ct < 4; ++ct)
            bfr[ct] = *(bf16x8*)&Ws[(cbase + ct * 16 + ln) * 136 + ko];
#pragma unroll
        for (int rt = 0; rt < 4; ++rt)
#pragma unroll
            for (int ct = 0; ct < 4; ++ct)
                acc[rt][ct] = __builtin_amdgcn_mfma_f32_16x16x32_bf16(af[rt], bfr[ct],
                                                                      acc[rt][ct], 0, 0, 0);
    }

    // x epilogue: relu(acc + b2) -> Xs (or global if LAST)
    float bsv[4];
#pragma unroll
    for (int ct = 0; ct < 4; ++ct) bsv[ct] = b2[cbase + ct * 16 + ln];
#pragma unroll
    for (int rt = 0; rt < 4; ++rt) {
        int lr0 = lrbase + rt * 16 + q * 4;
#pragma unroll
        for (int i = 0; i < 4; ++i) {
            int lr = lr0 + i;
            int gr = row0 + lr;
#pragma unroll
            for (int ct = 0; ct < 4; ++ct) {
                float xv = (gr < N_NODES) ? fmaxf(acc[rt][ct][i] + bsv[ct], 0.f) : 0.f;
                if (LAST) {
                    if (gr < N_NODES) outb[(size_t)gr * 128 + cbase + ct * 16 + ln] = f2b(xv);
                } else {
                    Xs[lr * 136 + cbase + ct * 16 + ln] = f2b(xv);
                }
            }
        }
    }

    if (!LAST) {
        __syncthreads();
#pragma unroll
        for (int i = 0; i < 8; ++i) {
            int chunk = tid + 256 * i;
            int n = chunk >> 4;
            int k8 = (chunk & 15) * 8;
            *(bf16x8*)&Ws[n * 136 + k8] = *(const bf16x8*)&Wt1n[n * 128 + k8];
        }
        __syncthreads();

#pragma unroll
        for (int rt = 0; rt < 4; ++rt)
#pragma unroll
            for (int ct = 0; ct < 4; ++ct) acc[rt][ct] = z4;

#pragma unroll
        for (int ks = 0; ks < 4; ++ks) {
            int ko = ks * 32 + q * 8;
            bf16x8 af[4], bfr[4];
#pragma unroll
            for (int rt = 0; rt < 4; ++rt)
                af[rt] = *(bf16x8*)&Xs[(lrbase + rt * 16 + ln) * 136 + ko];
#pragma unroll
            for (int ct = 0; ct < 4; ++ct)
                bfr[ct] = *(bf16x8*)&Ws[(cbase + ct * 16 + ln) * 136 + ko];
#pragma unroll
            for (int rt = 0; rt < 4; ++rt)
#pragma unroll
                for (int ct = 0; ct < 4; ++ct)
                    acc[rt][ct] = __builtin_amdgcn_mfma_f32_16x16x32_bf16(af[rt], bfr[ct],
                                                                          acc[rt][ct], 0, 0, 0);
        }
#pragma unroll
        for (int rt = 0; rt < 4; ++rt) {
            int gr0 = row0 + lrbase + rt * 16 + q * 4;
#pragma unroll
            for (int i = 0; i < 4; ++i) {
                int gr = gr0 + i;
                if (gr < N_NODES) {
#pragma unroll
                    for (int ct = 0; ct < 4; ++ct)
                        outb[(size_t)gr * 128 + cbase + ct * 16 + ln] = f2b(acc[rt][ct][i]);
                }
            }
        }
    }
}

// ---- fused pool + head: block = graph; binary-search bounds, pool, MLP ------
__global__ __launch_bounds__(128) void k_poolhead(const unsigned short* __restrict__ xb,
                                                  const void* batch,
                                                  const int* __restrict__ flag,
                                                  const float* __restrict__ fW1,
                                                  const float* __restrict__ fb1,
                                                  const float* __restrict__ fW2,
                                                  const float* __restrict__ fb2,
                                                  float* __restrict__ out) {
    __shared__ float gs[128];
    __shared__ float hs[128];
    int b = blockIdx.x, t = threadIdx.x;
    int f = *flag;
    int lo = 0, hi = N_NODES;
    while (lo < hi) {
        int mid = (lo + hi) >> 1;
        if (geti(batch, mid, f) < b) lo = mid + 1;
        else hi = mid;
    }
    int s = lo;
    hi = N_NODES;
    while (lo < hi) {
        int mid = (lo + hi) >> 1;
        if (geti(batch, mid, f) < b + 1) lo = mid + 1;
        else hi = mid;
    }
    int e = lo;
    float acc = 0.f;
    for (int i = s; i < e; ++i) acc += b2f(xb[(size_t)i * 128 + t]);
    gs[t] = acc;
    __syncthreads();
    float a = fb1[t];
    for (int k = 0; k < 128; ++k) a += gs[k] * fW1[k * 128 + t];
    hs[t] = fmaxf(a, 0.f);
    __syncthreads();
    if (t < 64) {
        float o = fb2[t];
        for (int k = 0; k < 128; ++k) o += hs[k] * fW2[k * 64 + t];
        out[(size_t)b * 64 + t] = o;
    }
}

extern "C" void kernel_launch(void* const* d_in, const int* in_sizes, int n_in,
                              void* d_out, int out_size, void* d_ws, size_t ws_size,
                              hipStream_t stream) {
    const float* x     = (const float*)d_in[0];
    const void*  ei    = d_in[1];
    const void*  batch = d_in[2];
    const float* W1    = (const float*)d_in[3];
    const float* gamma = (const float*)d_in[5];
    const float* beta  = (const float*)d_in[6];
    const float* W2    = (const float*)d_in[7];
    const float* b2    = (const float*)d_in[8];
    const float* fW1   = (const float*)d_in[9];
    const float* fb1   = (const float*)d_in[10];
    const float* fW2   = (const float*)d_in[11];
    const float* fb2   = (const float*)d_in[12];
    float* out = (float*)d_out;

    // workspace layout (all chunks multiple of 16 B); deg+stats contiguous for
    // a single zero-fill memset.
    unsigned short* ub = (unsigned short*)d_ws;                    // 12.8M us
    unsigned short* zb = ub + (size_t)N_NODES * D;                 // 12.8M us
    unsigned short* xb = zb + (size_t)N_NODES * D;                 // 12.8M us (final x)
    int* deg    = (int*)(xb + (size_t)N_NODES * D);                // 100,000
    float* stats = (float*)(deg + N_NODES);                        // 768 (zeroed w/ deg)
    int* rowp   = (int*)(stats + NL * 256);                        // 100,004 (padded)
    int* eidx   = rowp + 100004;                                   // 1,600,000
    unsigned int* tmp = (unsigned int*)(eidx + N_EDGES);           // 1,600,000
    int* dflag  = (int*)(tmp + N_EDGES);                           // 4
    int* bsum   = dflag + 4;                                       // 128
    int* boff   = bsum + 128;                                      // 128
    int* gcur   = boff + 128;                                      // 512
    unsigned short* Wt = (unsigned short*)(gcur + 512);            // 6*16384 us

    hipMemsetAsync(deg, 0, (N_NODES + NL * 256) * sizeof(int), stream);

    k_wprep<<<dim3(128, 2 * NL), 128, 0, stream>>>(W1, W2, Wt, ei, dflag);
    k_hist<<<(N_EDGES + 255) / 256, 256, 0, stream>>>(ei, dflag, deg);
    k_scan1<<<98, 256, 0, stream>>>(deg, bsum);
    k_scan2<<<1, 64, 0, stream>>>(bsum, boff, rowp);
    k_scan3<<<98, 256, 0, stream>>>(deg, boff, rowp, gcur);
    k_part<<<(N_EDGES + EPB - 1) / EPB, 256, 0, stream>>>(ei, dflag, gcur, tmp);
    k_fscat<<<NB, 256, 0, stream>>>(tmp, rowp, eidx);

    const int gemm_grid = (N_NODES + 127) / 128;  // 782

    k_gemm0<<<gemm_grid, 256, 0, stream>>>(x, Wt, ub);
    for (int l = 0; l < NL; ++l) {
        k_agz<<<N_NODES / 4, 256, 0, stream>>>(ub, rowp, eidx, zb);
        k_zstats<<<256, 256, 0, stream>>>(zb, stats + (size_t)l * 256);
        if (l < NL - 1) {
            k_gemm2f<0><<<gemm_grid, 256, 0, stream>>>(
                zb, Wt + (size_t)(NL + l) * D * D, Wt + (size_t)(l + 1) * D * D,
                b2 + (size_t)l * D, stats + (size_t)l * 256,
                gamma + (size_t)l * D, beta + (size_t)l * D, ub);
        } else {
            k_gemm2f<1><<<gemm_grid, 256, 0, stream>>>(
                zb, Wt + (size_t)(NL + l) * D * D, nullptr,
                b2 + (size_t)l * D, stats + (size_t)l * 256,
                gamma + (size_t)l * D, beta + (size_t)l * D, xb);
        }
    }

    k_poolhead<<<N_GRAPHS, 128, 0, stream>>>(xb, batch, dflag, fW1, fb1, fW2, fb2, out);
}

// Round 12
// 581.525 us; speedup vs baseline: 1.2866x; 1.1360x over previous
//
#include <hip/hip_runtime.h>

#define N_NODES 100000
#define N_EDGES 1600000
#define N_GRAPHS 1024
#define D 128
#define NL 3
#define BN_EPS 1e-5f
#define BG 196                                  // dst nodes per bucket
#define NB ((N_NODES + BG - 1) / BG)            // 511 buckets
#define EPB 4096                                // edges per partition block

typedef __attribute__((ext_vector_type(8))) short bf16x8;
typedef __attribute__((ext_vector_type(4))) float f32x4;

__device__ __forceinline__ unsigned short f2b(float f) {
    unsigned int u = __float_as_uint(f);
    u += 0x7fff + ((u >> 16) & 1);   // round to nearest even
    return (unsigned short)(u >> 16);
}
__device__ __forceinline__ float b2f(unsigned short b) {
    return __uint_as_float(((unsigned int)b) << 16);
}

__device__ __forceinline__ int geti(const void* p, long long i, int f64) {
    return f64 ? (int)((const long long*)p)[i] : ((const int*)p)[i];
}

// ------- weight prep: Wt[m][n][k] = bf16(W[m][k][n]); block(0,0) also detects
// the edge-index dtype (int64 vs int32) into *flag.
__global__ void k_wprep(const float* __restrict__ W1, const float* __restrict__ W2,
                        unsigned short* __restrict__ Wt, const void* ei, int* flag) {
    int m = blockIdx.y;
    int k = blockIdx.x;
    int n = threadIdx.x;
    const float* src = (m < NL) ? (W1 + (size_t)m * D * D) : (W2 + (size_t)(m - NL) * D * D);
    Wt[(size_t)m * D * D + n * D + k] = f2b(src[k * D + n]);
    if (blockIdx.x == 0 && blockIdx.y == 0 && threadIdx.x < 64) {
        int t = threadIdx.x;
        const int* p = (const int*)ei;
        int acc = p[2 * t + 1] | p[2 * (t + 64) + 1];
        unsigned long long b = __ballot(acc != 0);
        if (t == 0) *flag = (b == 0ULL) ? 1 : 0;
    }
}

// ---- bucket-level edge count: LDS hist over 511 buckets, one flush/block ----
__global__ __launch_bounds__(256) void k_bcount(const void* ei, const int* __restrict__ flag,
                                                int* __restrict__ bcnt) {
    __shared__ int hist[NB];
    int tid = threadIdx.x;
    long long e0 = (long long)blockIdx.x * EPB;
    int f = *flag;
    for (int b = tid; b < NB; b += 256) hist[b] = 0;
    __syncthreads();
#pragma unroll
    for (int i = 0; i < EPB / 256; ++i) {
        long long e = e0 + i * 256 + tid;
        if (e < N_EDGES) {
            int d = geti(ei, (long long)N_EDGES + e, f);
            atomicAdd(&hist[d / BG], 1);
        }
    }
    __syncthreads();
    for (int b = tid; b < NB; b += 256) {
        int h = hist[b];
        if (h) atomicAdd(&bcnt[b], h);
    }
}

// ---- bucket prefix scan (511 entries, 1 block): bbase/gcur; rowp[N]=E ----
__global__ void k_bscan(const int* __restrict__ bcnt, int* __restrict__ bbase,
                        int* __restrict__ gcur, int* __restrict__ rowp) {
    __shared__ int wtot[4];
    int tid = threadIdx.x;           // 256
    int lane = tid & 63, w = tid >> 6;
    int i0 = 2 * tid, i1 = 2 * tid + 1;
    int a = (i0 < NB) ? bcnt[i0] : 0;
    int b = (i1 < NB) ? bcnt[i1] : 0;
    int p = a + b;
    int incl = p;
    for (int off = 1; off < 64; off <<= 1) {
        int v = __shfl_up(incl, off, 64);
        if (lane >= off) incl += v;
    }
    if (lane == 63) wtot[w] = incl;
    __syncthreads();
    int woff = 0;
    for (int w2 = 0; w2 < w; ++w2) woff += wtot[w2];
    int ex = woff + incl - p;
    if (i0 <= NB) { bbase[i0] = ex; gcur[i0] = ex; }
    if (i1 <= NB) { bbase[i1] = ex + a; gcur[i1] = ex + a; }
    if (tid == 0) rowp[N_NODES] = N_EDGES;
}

// ---- partition edges into NB coarse dst-buckets, packed (dl<<17|src) --------
__global__ __launch_bounds__(256) void k_part(const void* ei, const int* __restrict__ flag,
                                              int* __restrict__ gcur,
                                              unsigned int* __restrict__ tmp) {
    __shared__ int hist[NB + 1];
    __shared__ int cur[NB + 1];
    int tid = threadIdx.x;
    long long e0 = (long long)blockIdx.x * EPB;
    int f = *flag;
    for (int b = tid; b < NB; b += 256) hist[b] = 0;
    __syncthreads();
#pragma unroll
    for (int i = 0; i < EPB / 256; ++i) {
        long long e = e0 + i * 256 + tid;
        if (e < N_EDGES) {
            int d = geti(ei, (long long)N_EDGES + e, f);
            atomicAdd(&hist[d / BG], 1);
        }
    }
    __syncthreads();
    for (int b = tid; b < NB; b += 256) {
        int h = hist[b];
        cur[b] = h ? atomicAdd(&gcur[b], h) : 0;
    }
    __syncthreads();
#pragma unroll
    for (int i = 0; i < EPB / 256; ++i) {
        long long e = e0 + i * 256 + tid;
        if (e < N_EDGES) {
            int d = geti(ei, (long long)N_EDGES + e, f);
            int s = geti(ei, e, f);
            int b = d / BG;
            int pos = atomicAdd(&cur[b], 1);
            tmp[pos] = ((unsigned int)(d - b * BG) << 17) | (unsigned int)s;
        }
    }
}

// ---- per-bucket: build deg in LDS, local prefix -> rowp, scatter to eidx ----
__global__ __launch_bounds__(256) void k_fscat(const unsigned int* __restrict__ tmp,
                                               const int* __restrict__ bbase,
                                               int* __restrict__ rowp,
                                               int* __restrict__ eidx) {
    __shared__ int deg[BG];
    __shared__ int cur[BG];
    __shared__ int wtot[4];
    __shared__ int s_se[2];
    int b = blockIdx.x;
    int nb = b * BG;
    int nn = min(BG, N_NODES - nb);
    int tid = threadIdx.x;
    int lane = tid & 63, w = tid >> 6;
    if (tid < nn) deg[tid] = 0;
    if (tid == 0) s_se[0] = bbase[b];
    if (tid == 1) s_se[1] = bbase[b + 1];
    __syncthreads();
    int s = s_se[0], e = s_se[1];
    // pass 1: per-dst counts
    for (int t = s + tid; t < e; t += 256) atomicAdd(&deg[tmp[t] >> 17], 1);
    __syncthreads();
    // exclusive prefix over nn (<=196) entries, 4-wave shuffle scan
    int val = (tid < nn) ? deg[tid] : 0;
    int incl = val;
    for (int off = 1; off < 64; off <<= 1) {
        int v = __shfl_up(incl, off, 64);
        if (lane >= off) incl += v;
    }
    if (lane == 63) wtot[w] = incl;
    __syncthreads();
    int woff = 0;
    for (int w2 = 0; w2 < w; ++w2) woff += wtot[w2];
    int ex = s + woff + incl - val;
    if (tid < nn) {
        cur[tid] = ex;
        rowp[nb + tid] = ex;
    }
    __syncthreads();
    // pass 2: scatter within bucket (L2-local)
    for (int t = s + tid; t < e; t += 256) {
        unsigned int u = tmp[t];
        int dl = u >> 17;
        int pos = atomicAdd(&cur[dl], 1);
        eidx[pos] = (int)(u & 0x1FFFF);
    }
}

// ---------------- GEMM0: u0 = bf16(x) @ W1_0 (fp32 A direct, W in LDS) -------
__global__ __launch_bounds__(256) void k_gemm0(const float* __restrict__ x,
                                               const unsigned short* __restrict__ Wt,
                                               unsigned short* __restrict__ ub) {
    __shared__ unsigned short Ws[128 * 136];
    int tid = threadIdx.x;
    int row0 = blockIdx.x * 128;
#pragma unroll
    for (int i = 0; i < 8; ++i) {
        int chunk = tid + 256 * i;
        int n = chunk >> 4;
        int k8 = (chunk & 15) * 8;
        *(bf16x8*)&Ws[n * 136 + k8] = *(const bf16x8*)&Wt[n * 128 + k8];
    }
    __syncthreads();

    int w = tid >> 6, lane = tid & 63, q = lane >> 4, ln = lane & 15;
    int rbase = row0 + (w & 1) * 64, cbase = (w >> 1) * 64;

    f32x4 acc[4][4];
    f32x4 z4 = {0.f, 0.f, 0.f, 0.f};
#pragma unroll
    for (int rt = 0; rt < 4; ++rt)
#pragma unroll
        for (int ct = 0; ct < 4; ++ct) acc[rt][ct] = z4;

#pragma unroll
    for (int ks = 0; ks < 4; ++ks) {
        int ko = ks * 32 + q * 8;
        bf16x8 af[4];
#pragma unroll
        for (int rt = 0; rt < 4; ++rt) {
            int row = rbase + rt * 16 + ln;
            bf16x8 v = {0, 0, 0, 0, 0, 0, 0, 0};
            if (row < N_NODES) {
                float4 p0 = *(const float4*)&x[(size_t)row * 128 + ko];
                float4 p1 = *(const float4*)&x[(size_t)row * 128 + ko + 4];
                v[0] = (short)f2b(p0.x); v[1] = (short)f2b(p0.y);
                v[2] = (short)f2b(p0.z); v[3] = (short)f2b(p0.w);
                v[4] = (short)f2b(p1.x); v[5] = (short)f2b(p1.y);
                v[6] = (short)f2b(p1.z); v[7] = (short)f2b(p1.w);
            }
            af[rt] = v;
        }
        bf16x8 bfr[4];
#pragma unroll
        for (int ct = 0; ct < 4; ++ct)
            bfr[ct] = *(bf16x8*)&Ws[(cbase + ct * 16 + ln) * 136 + ko];
#pragma unroll
        for (int rt = 0; rt < 4; ++rt)
#pragma unroll
            for (int ct = 0; ct < 4; ++ct)
                acc[rt][ct] = __builtin_amdgcn_mfma_f32_16x16x32_bf16(af[rt], bfr[ct],
                                                                      acc[rt][ct], 0, 0, 0);
    }
#pragma unroll
    for (int rt = 0; rt < 4; ++rt) {
        int gr0 = rbase + rt * 16 + q * 4;
#pragma unroll
        for (int i = 0; i < 4; ++i) {
            int gr = gr0 + i;
            if (gr < N_NODES) {
#pragma unroll
                for (int ct = 0; ct < 4; ++ct)
                    ub[(size_t)gr * 128 + cbase + ct * 16 + ln] = f2b(acc[rt][ct][i]);
            }
        }
    }
}

// ---- aggregation in u-space: z = u_i + sum_j u_j (b1 dropped: BN-invariant) --
__global__ void k_agz(const unsigned short* __restrict__ ub, const int* __restrict__ rowp,
                      const int* __restrict__ eidx, unsigned short* __restrict__ zb) {
    int wid = threadIdx.x >> 6;
    int lane = threadIdx.x & 63;
    int node = blockIdx.x * 4 + wid;
    const unsigned int* u1 = (const unsigned int*)ub;   // 64 dwords per row
    unsigned int u = u1[(size_t)node * 64 + lane];
    float accx = __uint_as_float(u << 16);
    float accy = __uint_as_float(u & 0xffff0000u);
    int s = rowp[node], e = rowp[node + 1];
    int i = s;
    for (; i + 7 < e; i += 8) {
        unsigned int v0 = u1[(size_t)eidx[i] * 64 + lane];
        unsigned int v1 = u1[(size_t)eidx[i + 1] * 64 + lane];
        unsigned int v2 = u1[(size_t)eidx[i + 2] * 64 + lane];
        unsigned int v3 = u1[(size_t)eidx[i + 3] * 64 + lane];
        unsigned int v4 = u1[(size_t)eidx[i + 4] * 64 + lane];
        unsigned int v5 = u1[(size_t)eidx[i + 5] * 64 + lane];
        unsigned int v6 = u1[(size_t)eidx[i + 6] * 64 + lane];
        unsigned int v7 = u1[(size_t)eidx[i + 7] * 64 + lane];
        accx += __uint_as_float(v0 << 16) + __uint_as_float(v1 << 16) +
                __uint_as_float(v2 << 16) + __uint_as_float(v3 << 16) +
                __uint_as_float(v4 << 16) + __uint_as_float(v5 << 16) +
                __uint_as_float(v6 << 16) + __uint_as_float(v7 << 16);
        accy += __uint_as_float(v0 & 0xffff0000u) + __uint_as_float(v1 & 0xffff0000u) +
                __uint_as_float(v2 & 0xffff0000u) + __uint_as_float(v3 & 0xffff0000u) +
                __uint_as_float(v4 & 0xffff0000u) + __uint_as_float(v5 & 0xffff0000u) +
                __uint_as_float(v6 & 0xffff0000u) + __uint_as_float(v7 & 0xffff0000u);
    }
    for (; i + 1 < e; i += 2) {
        unsigned int v0 = u1[(size_t)eidx[i] * 64 + lane];
        unsigned int v1 = u1[(size_t)eidx[i + 1] * 64 + lane];
        accx += __uint_as_float(v0 << 16) + __uint_as_float(v1 << 16);
        accy += __uint_as_float(v0 & 0xffff0000u) + __uint_as_float(v1 & 0xffff0000u);
    }
    if (i < e) {
        unsigned int v0 = u1[(size_t)eidx[i] * 64 + lane];
        accx += __uint_as_float(v0 << 16);
        accy += __uint_as_float(v0 & 0xffff0000u);
    }
    unsigned int o = ((unsigned int)f2b(accy) << 16) | f2b(accx);
    ((unsigned int*)zb)[(size_t)node * 64 + lane] = o;
}

// ---- per-feature sum/sumsq over zb (streaming, two-level reduction) ---------
__global__ __launch_bounds__(256) void k_zstats(const unsigned short* __restrict__ zb,
                                                float* __restrict__ stats) {
    __shared__ float s_sum[128];
    __shared__ float s_sq[128];
    int tid = threadIdx.x;
    if (tid < 128) {
        s_sum[tid] = 0.f;
        s_sq[tid] = 0.f;
    }
    __syncthreads();
    int lane = tid & 63, w = tid >> 6;
    const unsigned int* z1 = (const unsigned int*)zb;
    float psx = 0.f, psy = 0.f, pqx = 0.f, pqy = 0.f;
    const int R = (N_NODES + 255) / 256;    // rows per block (ceil)
    int row0 = blockIdx.x * R;
    int row1 = min(row0 + R, N_NODES);
    for (int row = row0 + w; row < row1; row += 4) {
        unsigned int v = z1[(size_t)row * 64 + lane];
        float zx = __uint_as_float(v << 16);
        float zy = __uint_as_float(v & 0xffff0000u);
        psx += zx; pqx += zx * zx;
        psy += zy; pqy += zy * zy;
    }
    atomicAdd(&s_sum[2 * lane], psx);
    atomicAdd(&s_sum[2 * lane + 1], psy);
    atomicAdd(&s_sq[2 * lane], pqx);
    atomicAdd(&s_sq[2 * lane + 1], pqy);
    __syncthreads();
    if (tid < 128) {
        atomicAdd(&stats[tid], s_sum[tid]);
        atomicAdd(&stats[128 + tid], s_sq[tid]);
    }
}

// ---- GEMM2 fused: x = relu(BN(z)@W2+b2); if !LAST also u' = x@W1next -------
template <int LAST>
__global__ __launch_bounds__(256) void k_gemm2f(const unsigned short* __restrict__ zb,
                                                const unsigned short* __restrict__ Wt2,
                                                const unsigned short* __restrict__ Wt1n,
                                                const float* __restrict__ b2,
                                                const float* __restrict__ stats,
                                                const float* __restrict__ gamma,
                                                const float* __restrict__ beta,
                                                unsigned short* __restrict__ outb) {
    __shared__ unsigned short Ws[128 * 136];
    __shared__ unsigned short Xs[128 * 136];
    __shared__ float s_a[128];
    __shared__ float s_b[128];

    int tid = threadIdx.x;
    int row0 = blockIdx.x * 128;

#pragma unroll
    for (int i = 0; i < 8; ++i) {
        int chunk = tid + 256 * i;
        int n = chunk >> 4;
        int k8 = (chunk & 15) * 8;
        *(bf16x8*)&Ws[n * 136 + k8] = *(const bf16x8*)&Wt2[n * 128 + k8];
    }
    if (tid < 128) {
        float s1 = stats[tid];
        float s2 = stats[128 + tid];
        float mu = s1 / (float)N_NODES;
        float var = s2 / (float)N_NODES - mu * mu;
        float sc = rsqrtf(var + BN_EPS) * gamma[tid];
        s_a[tid] = sc;
        s_b[tid] = beta[tid] - mu * sc;
    }
    __syncthreads();

    int w = tid >> 6, lane = tid & 63, q = lane >> 4, ln = lane & 15;
    int lrbase = (w & 1) * 64, cbase = (w >> 1) * 64;

    f32x4 acc[4][4];
    f32x4 z4 = {0.f, 0.f, 0.f, 0.f};
#pragma unroll
    for (int rt = 0; rt < 4; ++rt)
#pragma unroll
        for (int ct = 0; ct < 4; ++ct) acc[rt][ct] = z4;

#pragma unroll
    for (int ks = 0; ks < 4; ++ks) {
        int ko = ks * 32 + q * 8;
        float scv[8], shv[8];
        *(float4*)&scv[0] = *(const float4*)&s_a[ko];
        *(float4*)&scv[4] = *(const float4*)&s_a[ko + 4];
        *(float4*)&shv[0] = *(const float4*)&s_b[ko];
        *(float4*)&shv[4] = *(const float4*)&s_b[ko + 4];
        bf16x8 af[4];
#pragma unroll
        for (int rt = 0; rt < 4; ++rt) {
            int row = row0 + lrbase + rt * 16 + ln;
            bf16x8 v = {0, 0, 0, 0, 0, 0, 0, 0};
            if (row < N_NODES) v = *(const bf16x8*)&zb[(size_t)row * 128 + ko];
            bf16x8 o;
#pragma unroll
            for (int t = 0; t < 8; ++t) {
                float xv = b2f((unsigned short)v[t]);
                o[t] = (short)f2b(fmaxf(xv * scv[t] + shv[t], 0.f));
            }
            af[rt] = o;
        }
        bf16x8 bfr[4];
#pragma unroll
        for (int ct = 0; ct < 4; ++ct)
            bfr[ct] = *(bf16x8*)&Ws[(cbase + ct * 16 + ln) * 136 + ko];
#pragma unroll
        for (int rt = 0; rt < 4; ++rt)
#pragma unroll
            for (int ct = 0; ct < 4; ++ct)
                acc[rt][ct] = __builtin_amdgcn_mfma_f32_16x16x32_bf16(af[rt], bfr[ct],
                                                                      acc[rt][ct], 0, 0, 0);
    }

    // x epilogue: relu(acc + b2) -> Xs (or global if LAST)
    float bsv[4];
#pragma unroll
    for (int ct = 0; ct < 4; ++ct) bsv[ct] = b2[cbase + ct * 16 + ln];
#pragma unroll
    for (int rt = 0; rt < 4; ++rt) {
        int lr0 = lrbase + rt * 16 + q * 4;
#pragma unroll
        for (int i = 0; i < 4; ++i) {
            int lr = lr0 + i;
            int gr = row0 + lr;
#pragma unroll
            for (int ct = 0; ct < 4; ++ct) {
                float xv = (gr < N_NODES) ? fmaxf(acc[rt][ct][i] + bsv[ct], 0.f) : 0.f;
                if (LAST) {
                    if (gr < N_NODES) outb[(size_t)gr * 128 + cbase + ct * 16 + ln] = f2b(xv);
                } else {
                    Xs[lr * 136 + cbase + ct * 16 + ln] = f2b(xv);
                }
            }
        }
    }

    if (!LAST) {
        __syncthreads();
#pragma unroll
        for (int i = 0; i < 8; ++i) {
            int chunk = tid + 256 * i;
            int n = chunk >> 4;
            int k8 = (chunk & 15) * 8;
            *(bf16x8*)&Ws[n * 136 + k8] = *(const bf16x8*)&Wt1n[n * 128 + k8];
        }
        __syncthreads();

#pragma unroll
        for (int rt = 0; rt < 4; ++rt)
#pragma unroll
            for (int ct = 0; ct < 4; ++ct) acc[rt][ct] = z4;

#pragma unroll
        for (int ks = 0; ks < 4; ++ks) {
            int ko = ks * 32 + q * 8;
            bf16x8 af[4], bfr[4];
#pragma unroll
            for (int rt = 0; rt < 4; ++rt)
                af[rt] = *(bf16x8*)&Xs[(lrbase + rt * 16 + ln) * 136 + ko];
#pragma unroll
            for (int ct = 0; ct < 4; ++ct)
                bfr[ct] = *(bf16x8*)&Ws[(cbase + ct * 16 + ln) * 136 + ko];
#pragma unroll
            for (int rt = 0; rt < 4; ++rt)
#pragma unroll
                for (int ct = 0; ct < 4; ++ct)
                    acc[rt][ct] = __builtin_amdgcn_mfma_f32_16x16x32_bf16(af[rt], bfr[ct],
                                                                          acc[rt][ct], 0, 0, 0);
        }
#pragma unroll
        for (int rt = 0; rt < 4; ++rt) {
            int gr0 = row0 + lrbase + rt * 16 + q * 4;
#pragma unroll
            for (int i = 0; i < 4; ++i) {
                int gr = gr0 + i;
                if (gr < N_NODES) {
#pragma unroll
                    for (int ct = 0; ct < 4; ++ct)
                        outb[(size_t)gr * 128 + cbase + ct * 16 + ln] = f2b(acc[rt][ct][i]);
                }
            }
        }
    }
}

// ---- fused pool + head: block = graph; binary-search bounds, pool, MLP ------
__global__ __launch_bounds__(128) void k_poolhead(const unsigned short* __restrict__ xb,
                                                  const void* batch,
                                                  const int* __restrict__ flag,
                                                  const float* __restrict__ fW1,
                                                  const float* __restrict__ fb1,
                                                  const float* __restrict__ fW2,
                                                  const float* __restrict__ fb2,
                                                  float* __restrict__ out) {
    __shared__ float gs[128];
    __shared__ float hs[128];
    int b = blockIdx.x, t = threadIdx.x;
    int f = *flag;
    int lo = 0, hi = N_NODES;
    while (lo < hi) {
        int mid = (lo + hi) >> 1;
        if (geti(batch, mid, f) < b) lo = mid + 1;
        else hi = mid;
    }
    int s = lo;
    hi = N_NODES;
    while (lo < hi) {
        int mid = (lo + hi) >> 1;
        if (geti(batch, mid, f) < b + 1) lo = mid + 1;
        else hi = mid;
    }
    int e = lo;
    float acc = 0.f;
    for (int i = s; i < e; ++i) acc += b2f(xb[(size_t)i * 128 + t]);
    gs[t] = acc;
    __syncthreads();
    float a = fb1[t];
    for (int k = 0; k < 128; ++k) a += gs[k] * fW1[k * 128 + t];
    hs[t] = fmaxf(a, 0.f);
    __syncthreads();
    if (t < 64) {
        float o = fb2[t];
        for (int k = 0; k < 128; ++k) o += hs[k] * fW2[k * 64 + t];
        out[(size_t)b * 64 + t] = o;
    }
}

extern "C" void kernel_launch(void* const* d_in, const int* in_sizes, int n_in,
                              void* d_out, int out_size, void* d_ws, size_t ws_size,
                              hipStream_t stream) {
    const float* x     = (const float*)d_in[0];
    const void*  ei    = d_in[1];
    const void*  batch = d_in[2];
    const float* W1    = (const float*)d_in[3];
    const float* gamma = (const float*)d_in[5];
    const float* beta  = (const float*)d_in[6];
    const float* W2    = (const float*)d_in[7];
    const float* b2    = (const float*)d_in[8];
    const float* fW1   = (const float*)d_in[9];
    const float* fb1   = (const float*)d_in[10];
    const float* fW2   = (const float*)d_in[11];
    const float* fb2   = (const float*)d_in[12];
    float* out = (float*)d_out;

    // workspace layout; stats+bcnt contiguous for a single zero-fill memset.
    unsigned short* ub = (unsigned short*)d_ws;                    // 12.8M us
    unsigned short* zb = ub + (size_t)N_NODES * D;                 // 12.8M us
    unsigned short* xb = zb + (size_t)N_NODES * D;                 // 12.8M us (final x)
    float* stats = (float*)(xb + (size_t)N_NODES * D);             // 768
    int* bcnt   = (int*)(stats + NL * 256);                        // 512 (zeroed w/ stats)
    int* rowp   = bcnt + 512;                                      // 100,004 (padded)
    int* eidx   = rowp + 100004;                                   // 1,600,000
    unsigned int* tmp = (unsigned int*)(eidx + N_EDGES);           // 1,600,000
    int* dflag  = (int*)(tmp + N_EDGES);                           // 4
    int* bbase  = dflag + 4;                                       // 512
    int* gcur   = bbase + 512;                                     // 512
    unsigned short* Wt = (unsigned short*)(gcur + 512);            // 6*16384 us

    hipMemsetAsync(stats, 0, (NL * 256 + 512) * sizeof(int), stream);

    k_wprep<<<dim3(128, 2 * NL), 128, 0, stream>>>(W1, W2, Wt, ei, dflag);
    const int part_grid = (N_EDGES + EPB - 1) / EPB;  // 391
    k_bcount<<<part_grid, 256, 0, stream>>>(ei, dflag, bcnt);
    k_bscan<<<1, 256, 0, stream>>>(bcnt, bbase, gcur, rowp);
    k_part<<<part_grid, 256, 0, stream>>>(ei, dflag, gcur, tmp);
    k_fscat<<<NB, 256, 0, stream>>>(tmp, bbase, rowp, eidx);

    const int gemm_grid = (N_NODES + 127) / 128;  // 782

    k_gemm0<<<gemm_grid, 256, 0, stream>>>(x, Wt, ub);
    for (int l = 0; l < NL; ++l) {
        k_agz<<<N_NODES / 4, 256, 0, stream>>>(ub, rowp, eidx, zb);
        k_zstats<<<256, 256, 0, stream>>>(zb, stats + (size_t)l * 256);
        if (l < NL - 1) {
            k_gemm2f<0><<<gemm_grid, 256, 0, stream>>>(
                zb, Wt + (size_t)(NL + l) * D * D, Wt + (size_t)(l + 1) * D * D,
                b2 + (size_t)l * D, stats + (size_t)l * 256,
                gamma + (size_t)l * D, beta + (size_t)l * D, ub);
        } else {
            k_gemm2f<1><<<gemm_grid, 256, 0, stream>>>(
                zb, Wt + (size_t)(NL + l) * D * D, nullptr,
                b2 + (size_t)l * D, stats + (size_t)l * 256,
                gamma + (size_t)l * D, beta + (size_t)l * D, xb);
        }
    }

    k_poolhead<<<N_GRAPHS, 128, 0, stream>>>(xb, batch, dflag, fW1, fb1, fW2, fb2, out);
}

// Round 13
// 566.468 us; speedup vs baseline: 1.3208x; 1.0266x over previous
//
#include <hip/hip_runtime.h>

#define N_NODES 100000
#define N_EDGES 1600000
#define N_GRAPHS 1024
#define D 128
#define NL 3
#define BN_EPS 1e-5f
#define BG 196                                  // dst nodes per bucket
#define NB ((N_NODES + BG - 1) / BG)            // 511 buckets
#define EPB 4096                                // edges per partition block

typedef __attribute__((ext_vector_type(8))) short bf16x8;
typedef __attribute__((ext_vector_type(4))) float f32x4;

__device__ __forceinline__ unsigned short f2b(float f) {
    unsigned int u = __float_as_uint(f);
    u += 0x7fff + ((u >> 16) & 1);   // round to nearest even
    return (unsigned short)(u >> 16);
}
__device__ __forceinline__ float b2f(unsigned short b) {
    return __uint_as_float(((unsigned int)b) << 16);
}

__device__ __forceinline__ int geti(const void* p, long long i, int f64) {
    return f64 ? (int)((const long long*)p)[i] : ((const int*)p)[i];
}

// ------- weight prep: Wt[m][n][k] = bf16(W[m][k][n]); block(0,0) also detects
// the edge-index dtype (int64 vs int32) into *flag.
__global__ void k_wprep(const float* __restrict__ W1, const float* __restrict__ W2,
                        unsigned short* __restrict__ Wt, const void* ei, int* flag) {
    int m = blockIdx.y;
    int k = blockIdx.x;
    int n = threadIdx.x;
    const float* src = (m < NL) ? (W1 + (size_t)m * D * D) : (W2 + (size_t)(m - NL) * D * D);
    Wt[(size_t)m * D * D + n * D + k] = f2b(src[k * D + n]);
    if (blockIdx.x == 0 && blockIdx.y == 0 && threadIdx.x < 64) {
        int t = threadIdx.x;
        const int* p = (const int*)ei;
        int acc = p[2 * t + 1] | p[2 * (t + 64) + 1];
        unsigned long long b = __ballot(acc != 0);
        if (t == 0) *flag = (b == 0ULL) ? 1 : 0;
    }
}

// ---- bucket-level edge count: LDS hist over 511 buckets, one flush/block ----
__global__ __launch_bounds__(256) void k_bcount(const void* ei, const int* __restrict__ flag,
                                                int* __restrict__ bcnt) {
    __shared__ int hist[NB];
    int tid = threadIdx.x;
    long long e0 = (long long)blockIdx.x * EPB;
    int f = *flag;
    for (int b = tid; b < NB; b += 256) hist[b] = 0;
    __syncthreads();
#pragma unroll
    for (int i = 0; i < EPB / 256; ++i) {
        long long e = e0 + i * 256 + tid;
        if (e < N_EDGES) {
            int d = geti(ei, (long long)N_EDGES + e, f);
            atomicAdd(&hist[d / BG], 1);
        }
    }
    __syncthreads();
    for (int b = tid; b < NB; b += 256) {
        int h = hist[b];
        if (h) atomicAdd(&bcnt[b], h);
    }
}

// ---- bucket prefix scan (511 entries, 1 block): bbase/gcur; rowp[N]=E ----
__global__ void k_bscan(const int* __restrict__ bcnt, int* __restrict__ bbase,
                        int* __restrict__ gcur, int* __restrict__ rowp) {
    __shared__ int wtot[4];
    int tid = threadIdx.x;           // 256
    int lane = tid & 63, w = tid >> 6;
    int i0 = 2 * tid, i1 = 2 * tid + 1;
    int a = (i0 < NB) ? bcnt[i0] : 0;
    int b = (i1 < NB) ? bcnt[i1] : 0;
    int p = a + b;
    int incl = p;
    for (int off = 1; off < 64; off <<= 1) {
        int v = __shfl_up(incl, off, 64);
        if (lane >= off) incl += v;
    }
    if (lane == 63) wtot[w] = incl;
    __syncthreads();
    int woff = 0;
    for (int w2 = 0; w2 < w; ++w2) woff += wtot[w2];
    int ex = woff + incl - p;
    if (i0 <= NB) { bbase[i0] = ex; gcur[i0] = ex; }
    if (i1 <= NB) { bbase[i1] = ex + a; gcur[i1] = ex + a; }
    if (tid == 0) rowp[N_NODES] = N_EDGES;
}

// ---- partition edges into NB coarse dst-buckets, packed (dl<<17|src) --------
__global__ __launch_bounds__(256) void k_part(const void* ei, const int* __restrict__ flag,
                                              int* __restrict__ gcur,
                                              unsigned int* __restrict__ tmp) {
    __shared__ int hist[NB + 1];
    __shared__ int cur[NB + 1];
    int tid = threadIdx.x;
    long long e0 = (long long)blockIdx.x * EPB;
    int f = *flag;
    for (int b = tid; b < NB; b += 256) hist[b] = 0;
    __syncthreads();
#pragma unroll
    for (int i = 0; i < EPB / 256; ++i) {
        long long e = e0 + i * 256 + tid;
        if (e < N_EDGES) {
            int d = geti(ei, (long long)N_EDGES + e, f);
            atomicAdd(&hist[d / BG], 1);
        }
    }
    __syncthreads();
    for (int b = tid; b < NB; b += 256) {
        int h = hist[b];
        cur[b] = h ? atomicAdd(&gcur[b], h) : 0;
    }
    __syncthreads();
#pragma unroll
    for (int i = 0; i < EPB / 256; ++i) {
        long long e = e0 + i * 256 + tid;
        if (e < N_EDGES) {
            int d = geti(ei, (long long)N_EDGES + e, f);
            int s = geti(ei, e, f);
            int b = d / BG;
            int pos = atomicAdd(&cur[b], 1);
            tmp[pos] = ((unsigned int)(d - b * BG) << 17) | (unsigned int)s;
        }
    }
}

// ---- per-bucket: build deg in LDS, local prefix -> rowp, scatter to eidx ----
__global__ __launch_bounds__(256) void k_fscat(const unsigned int* __restrict__ tmp,
                                               const int* __restrict__ bbase,
                                               int* __restrict__ rowp,
                                               int* __restrict__ eidx) {
    __shared__ int deg[BG];
    __shared__ int cur[BG];
    __shared__ int wtot[4];
    __shared__ int s_se[2];
    int b = blockIdx.x;
    int nb = b * BG;
    int nn = min(BG, N_NODES - nb);
    int tid = threadIdx.x;
    int lane = tid & 63, w = tid >> 6;
    if (tid < nn) deg[tid] = 0;
    if (tid == 0) s_se[0] = bbase[b];
    if (tid == 1) s_se[1] = bbase[b + 1];
    __syncthreads();
    int s = s_se[0], e = s_se[1];
    // pass 1: per-dst counts
    for (int t = s + tid; t < e; t += 256) atomicAdd(&deg[tmp[t] >> 17], 1);
    __syncthreads();
    // exclusive prefix over nn (<=196) entries, 4-wave shuffle scan
    int val = (tid < nn) ? deg[tid] : 0;
    int incl = val;
    for (int off = 1; off < 64; off <<= 1) {
        int v = __shfl_up(incl, off, 64);
        if (lane >= off) incl += v;
    }
    if (lane == 63) wtot[w] = incl;
    __syncthreads();
    int woff = 0;
    for (int w2 = 0; w2 < w; ++w2) woff += wtot[w2];
    int ex = s + woff + incl - val;
    if (tid < nn) {
        cur[tid] = ex;
        rowp[nb + tid] = ex;
    }
    __syncthreads();
    // pass 2: scatter within bucket (L2-local)
    for (int t = s + tid; t < e; t += 256) {
        unsigned int u = tmp[t];
        int dl = u >> 17;
        int pos = atomicAdd(&cur[dl], 1);
        eidx[pos] = (int)(u & 0x1FFFF);
    }
}

// ---------------- GEMM0: u0 = bf16(x) @ W1_0 (fp32 A direct, W in LDS) -------
__global__ __launch_bounds__(256) void k_gemm0(const float* __restrict__ x,
                                               const unsigned short* __restrict__ Wt,
                                               unsigned short* __restrict__ ub) {
    __shared__ unsigned short Ws[128 * 136];
    int tid = threadIdx.x;
    int row0 = blockIdx.x * 128;
#pragma unroll
    for (int i = 0; i < 8; ++i) {
        int chunk = tid + 256 * i;
        int n = chunk >> 4;
        int k8 = (chunk & 15) * 8;
        *(bf16x8*)&Ws[n * 136 + k8] = *(const bf16x8*)&Wt[n * 128 + k8];
    }
    __syncthreads();

    int w = tid >> 6, lane = tid & 63, q = lane >> 4, ln = lane & 15;
    int rbase = row0 + (w & 1) * 64, cbase = (w >> 1) * 64;

    f32x4 acc[4][4];
    f32x4 z4 = {0.f, 0.f, 0.f, 0.f};
#pragma unroll
    for (int rt = 0; rt < 4; ++rt)
#pragma unroll
        for (int ct = 0; ct < 4; ++ct) acc[rt][ct] = z4;

#pragma unroll
    for (int ks = 0; ks < 4; ++ks) {
        int ko = ks * 32 + q * 8;
        bf16x8 af[4];
#pragma unroll
        for (int rt = 0; rt < 4; ++rt) {
            int row = rbase + rt * 16 + ln;
            bf16x8 v = {0, 0, 0, 0, 0, 0, 0, 0};
            if (row < N_NODES) {
                float4 p0 = *(const float4*)&x[(size_t)row * 128 + ko];
                float4 p1 = *(const float4*)&x[(size_t)row * 128 + ko + 4];
                v[0] = (short)f2b(p0.x); v[1] = (short)f2b(p0.y);
                v[2] = (short)f2b(p0.z); v[3] = (short)f2b(p0.w);
                v[4] = (short)f2b(p1.x); v[5] = (short)f2b(p1.y);
                v[6] = (short)f2b(p1.z); v[7] = (short)f2b(p1.w);
            }
            af[rt] = v;
        }
        bf16x8 bfr[4];
#pragma unroll
        for (int ct = 0; ct < 4; ++ct)
            bfr[ct] = *(bf16x8*)&Ws[(cbase + ct * 16 + ln) * 136 + ko];
#pragma unroll
        for (int rt = 0; rt < 4; ++rt)
#pragma unroll
            for (int ct = 0; ct < 4; ++ct)
                acc[rt][ct] = __builtin_amdgcn_mfma_f32_16x16x32_bf16(af[rt], bfr[ct],
                                                                      acc[rt][ct], 0, 0, 0);
    }
#pragma unroll
    for (int rt = 0; rt < 4; ++rt) {
        int gr0 = rbase + rt * 16 + q * 4;
#pragma unroll
        for (int i = 0; i < 4; ++i) {
            int gr = gr0 + i;
            if (gr < N_NODES) {
#pragma unroll
                for (int ct = 0; ct < 4; ++ct)
                    ub[(size_t)gr * 128 + cbase + ct * 16 + ln] = f2b(acc[rt][ct][i]);
            }
        }
    }
}

// ---- aggregation in u-space: z = u_i + sum_j u_j (b1 dropped: BN-invariant) --
__global__ void k_agz(const unsigned short* __restrict__ ub, const int* __restrict__ rowp,
                      const int* __restrict__ eidx, unsigned short* __restrict__ zb) {
    int wid = threadIdx.x >> 6;
    int lane = threadIdx.x & 63;
    int node = blockIdx.x * 4 + wid;
    const unsigned int* u1 = (const unsigned int*)ub;   // 64 dwords per row
    unsigned int u = u1[(size_t)node * 64 + lane];
    float accx = __uint_as_float(u << 16);
    float accy = __uint_as_float(u & 0xffff0000u);
    int s = rowp[node], e = rowp[node + 1];
    int i = s;
    for (; i + 7 < e; i += 8) {
        unsigned int v0 = u1[(size_t)eidx[i] * 64 + lane];
        unsigned int v1 = u1[(size_t)eidx[i + 1] * 64 + lane];
        unsigned int v2 = u1[(size_t)eidx[i + 2] * 64 + lane];
        unsigned int v3 = u1[(size_t)eidx[i + 3] * 64 + lane];
        unsigned int v4 = u1[(size_t)eidx[i + 4] * 64 + lane];
        unsigned int v5 = u1[(size_t)eidx[i + 5] * 64 + lane];
        unsigned int v6 = u1[(size_t)eidx[i + 6] * 64 + lane];
        unsigned int v7 = u1[(size_t)eidx[i + 7] * 64 + lane];
        accx += __uint_as_float(v0 << 16) + __uint_as_float(v1 << 16) +
                __uint_as_float(v2 << 16) + __uint_as_float(v3 << 16) +
                __uint_as_float(v4 << 16) + __uint_as_float(v5 << 16) +
                __uint_as_float(v6 << 16) + __uint_as_float(v7 << 16);
        accy += __uint_as_float(v0 & 0xffff0000u) + __uint_as_float(v1 & 0xffff0000u) +
                __uint_as_float(v2 & 0xffff0000u) + __uint_as_float(v3 & 0xffff0000u) +
                __uint_as_float(v4 & 0xffff0000u) + __uint_as_float(v5 & 0xffff0000u) +
                __uint_as_float(v6 & 0xffff0000u) + __uint_as_float(v7 & 0xffff0000u);
    }
    for (; i + 1 < e; i += 2) {
        unsigned int v0 = u1[(size_t)eidx[i] * 64 + lane];
        unsigned int v1 = u1[(size_t)eidx[i + 1] * 64 + lane];
        accx += __uint_as_float(v0 << 16) + __uint_as_float(v1 << 16);
        accy += __uint_as_float(v0 & 0xffff0000u) + __uint_as_float(v1 & 0xffff0000u);
    }
    if (i < e) {
        unsigned int v0 = u1[(size_t)eidx[i] * 64 + lane];
        accx += __uint_as_float(v0 << 16);
        accy += __uint_as_float(v0 & 0xffff0000u);
    }
    unsigned int o = ((unsigned int)f2b(accy) << 16) | f2b(accx);
    ((unsigned int*)zb)[(size_t)node * 64 + lane] = o;
}

// ---- per-feature sum/sumsq over zb (streaming, two-level reduction) ---------
__global__ __launch_bounds__(256) void k_zstats(const unsigned short* __restrict__ zb,
                                                float* __restrict__ stats) {
    __shared__ float s_sum[128];
    __shared__ float s_sq[128];
    int tid = threadIdx.x;
    if (tid < 128) {
        s_sum[tid] = 0.f;
        s_sq[tid] = 0.f;
    }
    __syncthreads();
    int lane = tid & 63, w = tid >> 6;
    const unsigned int* z1 = (const unsigned int*)zb;
    float psx = 0.f, psy = 0.f, pqx = 0.f, pqy = 0.f;
    const int R = (N_NODES + 511) / 512;    // rows per block (ceil)
    int row0 = blockIdx.x * R;
    int row1 = min(row0 + R, N_NODES);
    for (int row = row0 + w; row < row1; row += 4) {
        unsigned int v = z1[(size_t)row * 64 + lane];
        float zx = __uint_as_float(v << 16);
        float zy = __uint_as_float(v & 0xffff0000u);
        psx += zx; pqx += zx * zx;
        psy += zy; pqy += zy * zy;
    }
    atomicAdd(&s_sum[2 * lane], psx);
    atomicAdd(&s_sum[2 * lane + 1], psy);
    atomicAdd(&s_sq[2 * lane], pqx);
    atomicAdd(&s_sq[2 * lane + 1], pqy);
    __syncthreads();
    if (tid < 128) {
        atomicAdd(&stats[tid], s_sum[tid]);
        atomicAdd(&stats[128 + tid], s_sq[tid]);
    }
}

// ---- GEMM2 fused: x = relu(BN(z)@W2+b2); if !LAST also u' = x@W1next -------
// BN(z) staged ONCE per element into Xs (halves BN VALU vs per-wave frag BN);
// both K-loops read A-frags via ds_read_b128. Xs is reused for x between
// stages; Ws is reused for W1next.
template <int LAST>
__global__ __launch_bounds__(256) void k_gemm2f(const unsigned short* __restrict__ zb,
                                                const unsigned short* __restrict__ Wt2,
                                                const unsigned short* __restrict__ Wt1n,
                                                const float* __restrict__ b2,
                                                const float* __restrict__ stats,
                                                const float* __restrict__ gamma,
                                                const float* __restrict__ beta,
                                                unsigned short* __restrict__ outb) {
    __shared__ unsigned short Ws[128 * 136];
    __shared__ unsigned short Xs[128 * 136];
    __shared__ float s_a[128];
    __shared__ float s_b[128];

    int tid = threadIdx.x;
    int row0 = blockIdx.x * 128;

    // stage Ws = W2; compute BN scale/shift
#pragma unroll
    for (int i = 0; i < 8; ++i) {
        int chunk = tid + 256 * i;
        int n = chunk >> 4;
        int k8 = (chunk & 15) * 8;
        *(bf16x8*)&Ws[n * 136 + k8] = *(const bf16x8*)&Wt2[n * 128 + k8];
    }
    if (tid < 128) {
        float s1 = stats[tid];
        float s2 = stats[128 + tid];
        float mu = s1 / (float)N_NODES;
        float var = s2 / (float)N_NODES - mu * mu;
        float sc = rsqrtf(var + BN_EPS) * gamma[tid];
        s_a[tid] = sc;
        s_b[tid] = beta[tid] - mu * sc;
    }
    __syncthreads();

    // stage relu(BN(z)) -> Xs, each element exactly once
#pragma unroll
    for (int i = 0; i < 8; ++i) {
        int chunk = tid + 256 * i;
        int row = chunk >> 4;
        int k8 = (chunk & 15) * 8;
        int gr = row0 + row;
        bf16x8 v = {0, 0, 0, 0, 0, 0, 0, 0};
        if (gr < N_NODES) v = *(const bf16x8*)&zb[(size_t)gr * 128 + k8];
        float4 sc0 = *(const float4*)&s_a[k8];
        float4 sc1 = *(const float4*)&s_a[k8 + 4];
        float4 sh0 = *(const float4*)&s_b[k8];
        float4 sh1 = *(const float4*)&s_b[k8 + 4];
        bf16x8 o;
        o[0] = (short)f2b(fmaxf(b2f((unsigned short)v[0]) * sc0.x + sh0.x, 0.f));
        o[1] = (short)f2b(fmaxf(b2f((unsigned short)v[1]) * sc0.y + sh0.y, 0.f));
        o[2] = (short)f2b(fmaxf(b2f((unsigned short)v[2]) * sc0.z + sh0.z, 0.f));
        o[3] = (short)f2b(fmaxf(b2f((unsigned short)v[3]) * sc0.w + sh0.w, 0.f));
        o[4] = (short)f2b(fmaxf(b2f((unsigned short)v[4]) * sc1.x + sh1.x, 0.f));
        o[5] = (short)f2b(fmaxf(b2f((unsigned short)v[5]) * sc1.y + sh1.y, 0.f));
        o[6] = (short)f2b(fmaxf(b2f((unsigned short)v[6]) * sc1.z + sh1.z, 0.f));
        o[7] = (short)f2b(fmaxf(b2f((unsigned short)v[7]) * sc1.w + sh1.w, 0.f));
        *(bf16x8*)&Xs[row * 136 + k8] = o;
    }
    __syncthreads();

    int w = tid >> 6, lane = tid & 63, q = lane >> 4, ln = lane & 15;
    int lrbase = (w & 1) * 64, cbase = (w >> 1) * 64;

    f32x4 acc[4][4];
    f32x4 z4 = {0.f, 0.f, 0.f, 0.f};
#pragma unroll
    for (int rt = 0; rt < 4; ++rt)
#pragma unroll
        for (int ct = 0; ct < 4; ++ct) acc[rt][ct] = z4;

    // stage 1 K-loop: A from Xs, B from Ws (pure ds_read + MFMA)
#pragma unroll
    for (int ks = 0; ks < 4; ++ks) {
        int ko = ks * 32 + q * 8;
        bf16x8 af[4], bfr[4];
#pragma unroll
        for (int rt = 0; rt < 4; ++rt)
            af[rt] = *(bf16x8*)&Xs[(lrbase + rt * 16 + ln) * 136 + ko];
#pragma unroll
        for (int ct = 0; ct < 4; ++ct)
            bfr[ct] = *(bf16x8*)&Ws[(cbase + ct * 16 + ln) * 136 + ko];
#pragma unroll
        for (int rt = 0; rt < 4; ++rt)
#pragma unroll
            for (int ct = 0; ct < 4; ++ct)
                acc[rt][ct] = __builtin_amdgcn_mfma_f32_16x16x32_bf16(af[rt], bfr[ct],
                                                                      acc[rt][ct], 0, 0, 0);
    }

    float bsv[4];
#pragma unroll
    for (int ct = 0; ct < 4; ++ct) bsv[ct] = b2[cbase + ct * 16 + ln];

    if (LAST) {
        // epilogue straight to global
#pragma unroll
        for (int rt = 0; rt < 4; ++rt) {
            int gr0 = row0 + lrbase + rt * 16 + q * 4;
#pragma unroll
            for (int i = 0; i < 4; ++i) {
                int gr = gr0 + i;
                if (gr < N_NODES) {
#pragma unroll
                    for (int ct = 0; ct < 4; ++ct) {
                        float xv = fmaxf(acc[rt][ct][i] + bsv[ct], 0.f);
                        outb[(size_t)gr * 128 + cbase + ct * 16 + ln] = f2b(xv);
                    }
                }
            }
        }
    } else {
        __syncthreads();   // all stage-1 reads of Xs/Ws complete
        // epilogue x -> Xs (overwrite); stage Ws = W1next
#pragma unroll
        for (int rt = 0; rt < 4; ++rt) {
            int lr0 = lrbase + rt * 16 + q * 4;
#pragma unroll
            for (int i = 0; i < 4; ++i) {
                int lr = lr0 + i;
                int gr = row0 + lr;
#pragma unroll
                for (int ct = 0; ct < 4; ++ct) {
                    float xv = (gr < N_NODES) ? fmaxf(acc[rt][ct][i] + bsv[ct], 0.f) : 0.f;
                    Xs[lr * 136 + cbase + ct * 16 + ln] = f2b(xv);
                }
            }
        }
#pragma unroll
        for (int i = 0; i < 8; ++i) {
            int chunk = tid + 256 * i;
            int n = chunk >> 4;
            int k8 = (chunk & 15) * 8;
            *(bf16x8*)&Ws[n * 136 + k8] = *(const bf16x8*)&Wt1n[n * 128 + k8];
        }
        __syncthreads();

#pragma unroll
        for (int rt = 0; rt < 4; ++rt)
#pragma unroll
            for (int ct = 0; ct < 4; ++ct) acc[rt][ct] = z4;

#pragma unroll
        for (int ks = 0; ks < 4; ++ks) {
            int ko = ks * 32 + q * 8;
            bf16x8 af[4], bfr[4];
#pragma unroll
            for (int rt = 0; rt < 4; ++rt)
                af[rt] = *(bf16x8*)&Xs[(lrbase + rt * 16 + ln) * 136 + ko];
#pragma unroll
            for (int ct = 0; ct < 4; ++ct)
                bfr[ct] = *(bf16x8*)&Ws[(cbase + ct * 16 + ln) * 136 + ko];
#pragma unroll
            for (int rt = 0; rt < 4; ++rt)
#pragma unroll
                for (int ct = 0; ct < 4; ++ct)
                    acc[rt][ct] = __builtin_amdgcn_mfma_f32_16x16x32_bf16(af[rt], bfr[ct],
                                                                          acc[rt][ct], 0, 0, 0);
        }
#pragma unroll
        for (int rt = 0; rt < 4; ++rt) {
            int gr0 = row0 + lrbase + rt * 16 + q * 4;
#pragma unroll
            for (int i = 0; i < 4; ++i) {
                int gr = gr0 + i;
                if (gr < N_NODES) {
#pragma unroll
                    for (int ct = 0; ct < 4; ++ct)
                        outb[(size_t)gr * 128 + cbase + ct * 16 + ln] = f2b(acc[rt][ct][i]);
                }
            }
        }
    }
}

// ---- fused pool + head: block = graph; binary-search bounds, pool, MLP ------
__global__ __launch_bounds__(128) void k_poolhead(const unsigned short* __restrict__ xb,
                                                  const void* batch,
                                                  const int* __restrict__ flag,
                                                  const float* __restrict__ fW1,
                                                  const float* __restrict__ fb1,
                                                  const float* __restrict__ fW2,
                                                  const float* __restrict__ fb2,
                                                  float* __restrict__ out) {
    __shared__ float gs[128];
    __shared__ float hs[128];
    int b = blockIdx.x, t = threadIdx.x;
    int f = *flag;
    int lo = 0, hi = N_NODES;
    while (lo < hi) {
        int mid = (lo + hi) >> 1;
        if (geti(batch, mid, f) < b) lo = mid + 1;
        else hi = mid;
    }
    int s = lo;
    hi = N_NODES;
    while (lo < hi) {
        int mid = (lo + hi) >> 1;
        if (geti(batch, mid, f) < b + 1) lo = mid + 1;
        else hi = mid;
    }
    int e = lo;
    float acc = 0.f;
    for (int i = s; i < e; ++i) acc += b2f(xb[(size_t)i * 128 + t]);
    gs[t] = acc;
    __syncthreads();
    float a = fb1[t];
    for (int k = 0; k < 128; ++k) a += gs[k] * fW1[k * 128 + t];
    hs[t] = fmaxf(a, 0.f);
    __syncthreads();
    if (t < 64) {
        float o = fb2[t];
        for (int k = 0; k < 128; ++k) o += hs[k] * fW2[k * 64 + t];
        out[(size_t)b * 64 + t] = o;
    }
}

extern "C" void kernel_launch(void* const* d_in, const int* in_sizes, int n_in,
                              void* d_out, int out_size, void* d_ws, size_t ws_size,
                              hipStream_t stream) {
    const float* x     = (const float*)d_in[0];
    const void*  ei    = d_in[1];
    const void*  batch = d_in[2];
    const float* W1    = (const float*)d_in[3];
    const float* gamma = (const float*)d_in[5];
    const float* beta  = (const float*)d_in[6];
    const float* W2    = (const float*)d_in[7];
    const float* b2    = (const float*)d_in[8];
    const float* fW1   = (const float*)d_in[9];
    const float* fb1   = (const float*)d_in[10];
    const float* fW2   = (const float*)d_in[11];
    const float* fb2   = (const float*)d_in[12];
    float* out = (float*)d_out;

    // workspace layout; stats+bcnt contiguous for a single zero-fill memset.
    unsigned short* ub = (unsigned short*)d_ws;                    // 12.8M us
    unsigned short* zb = ub + (size_t)N_NODES * D;                 // 12.8M us
    unsigned short* xb = zb + (size_t)N_NODES * D;                 // 12.8M us (final x)
    float* stats = (float*)(xb + (size_t)N_NODES * D);             // 768
    int* bcnt   = (int*)(stats + NL * 256);                        // 512 (zeroed w/ stats)
    int* rowp   = bcnt + 512;                                      // 100,004 (padded)
    int* eidx   = rowp + 100004;                                   // 1,600,000
    unsigned int* tmp = (unsigned int*)(eidx + N_EDGES);           // 1,600,000
    int* dflag  = (int*)(tmp + N_EDGES);                           // 4
    int* bbase  = dflag + 4;                                       // 512
    int* gcur   = bbase + 512;                                     // 512
    unsigned short* Wt = (unsigned short*)(gcur + 512);            // 6*16384 us

    hipMemsetAsync(stats, 0, (NL * 256 + 512) * sizeof(int), stream);

    k_wprep<<<dim3(128, 2 * NL), 128, 0, stream>>>(W1, W2, Wt, ei, dflag);
    const int part_grid = (N_EDGES + EPB - 1) / EPB;  // 391
    k_bcount<<<part_grid, 256, 0, stream>>>(ei, dflag, bcnt);
    k_bscan<<<1, 256, 0, stream>>>(bcnt, bbase, gcur, rowp);
    k_part<<<part_grid, 256, 0, stream>>>(ei, dflag, gcur, tmp);
    k_fscat<<<NB, 256, 0, stream>>>(tmp, bbase, rowp, eidx);

    const int gemm_grid = (N_NODES + 127) / 128;  // 782

    k_gemm0<<<gemm_grid, 256, 0, stream>>>(x, Wt, ub);
    for (int l = 0; l < NL; ++l) {
        k_agz<<<N_NODES / 4, 256, 0, stream>>>(ub, rowp, eidx, zb);
        k_zstats<<<512, 256, 0, stream>>>(zb, stats + (size_t)l * 256);
        if (l < NL - 1) {
            k_gemm2f<0><<<gemm_grid, 256, 0, stream>>>(
                zb, Wt + (size_t)(NL + l) * D * D, Wt + (size_t)(l + 1) * D * D,
                b2 + (size_t)l * D, stats + (size_t)l * 256,
                gamma + (size_t)l * D, beta + (size_t)l * D, ub);
        } else {
            k_gemm2f<1><<<gemm_grid, 256, 0, stream>>>(
                zb, Wt + (size_t)(NL + l) * D * D, nullptr,
                b2 + (size_t)l * D, stats + (size_t)l * 256,
                gamma + (size_t)l * D, beta + (size_t)l * D, xb);
        }
    }

    k_poolhead<<<N_GRAPHS, 128, 0, stream>>>(xb, batch, dflag, fW1, fb1, fW2, fb2, out);
}